// Round 1
// baseline (1873.295 us; speedup 1.0000x reference)
//
#include <hip/hip_runtime.h>

#define N_NODES 100000
#define N_EDGES 1600000
#define FEAT 32
#define HID 64
#define NCLS 10

// ---------------- degree / norm precompute ----------------

__global__ void deg_kernel(const int* __restrict__ col, float* __restrict__ deg, int nE) {
    int e = blockIdx.x * blockDim.x + threadIdx.x;
    if (e < nE) atomicAdd(&deg[col[e]], 1.0f);
}

__global__ void dinv_kernel(float* __restrict__ deg, int n) {
    int i = blockIdx.x * blockDim.x + threadIdx.x;
    if (i < n) {
        float d = deg[i];
        deg[i] = (d > 0.0f) ? rsqrtf(d) : 0.0f;
    }
}

__global__ void norm_kernel(const int* __restrict__ row, const int* __restrict__ col,
                            const float* __restrict__ dinv, float* __restrict__ norm, int nE) {
    int e = blockIdx.x * blockDim.x + threadIdx.x;
    if (e < nE) norm[e] = dinv[row[e]] * dinv[col[e]];
}

// ---------------- sparse propagation: dst[col] += norm * src[row] ----------------

template <int F, int LOGF>
__global__ void hop_kernel(const int* __restrict__ row, const int* __restrict__ col,
                           const float* __restrict__ norm, const float* __restrict__ src,
                           float* __restrict__ dst, int nE) {
    int gid = blockIdx.x * blockDim.x + threadIdx.x;
    if (gid >= nE * F) return;  // nE*F <= 102.4M, fits int32
    int e = gid >> LOGF;
    int f = gid & (F - 1);
    int r = row[e];
    int c = col[e];
    float v = norm[e] * src[r * F + f];
    atomicAdd(&dst[c * F + f], v);
}

// ---------------- small dense GEMM: C[n x CO] (=|+=) H[n x F] @ W[F x CO] (+ bias) ----------------

template <int F, int CO, int CPAD, int ROWS>
__global__ void dense_kernel(const float* __restrict__ H, const float* __restrict__ W,
                             const float* __restrict__ bias, float* __restrict__ C,
                             int n, int accum) {
    __shared__ float Ws[F * CO];
    __shared__ float Hs[ROWS][F];
    const int NT = CPAD * ROWS;
    int tid = threadIdx.y * CPAD + threadIdx.x;

    for (int i = tid; i < F * CO; i += NT) Ws[i] = W[i];

    int row0 = blockIdx.x * ROWS;
    for (int i = tid; i < ROWS * F; i += NT) {
        int rr = i / F;
        int ff = i & (F - 1);
        int r = row0 + rr;
        Hs[rr][ff] = (r < n) ? H[r * F + ff] : 0.0f;
    }
    __syncthreads();

    int c = threadIdx.x;
    int r = row0 + threadIdx.y;
    if (c < CO && r < n) {
        float acc = 0.0f;
#pragma unroll
        for (int kk = 0; kk < F; kk++) acc += Hs[threadIdx.y][kk] * Ws[kk * CO + c];
        int idx = r * CO + c;
        if (accum) C[idx] += acc;
        else       C[idx] = acc + (bias ? bias[c] : 0.0f);
    }
}

// ---------------- elementwise ----------------

__global__ void relu_kernel(const float* __restrict__ in, float* __restrict__ out, int n) {
    int i = blockIdx.x * blockDim.x + threadIdx.x;
    if (i < n) out[i] = fmaxf(in[i], 0.0f);
}

__global__ void lsm_kernel(float* __restrict__ out, int n) {
    int r = blockIdx.x * blockDim.x + threadIdx.x;
    if (r >= n) return;
    float v[NCLS];
    float m = -1e30f;
#pragma unroll
    for (int j = 0; j < NCLS; j++) {
        v[j] = out[r * NCLS + j];
        m = fmaxf(m, v[j]);
    }
    float s = 0.0f;
#pragma unroll
    for (int j = 0; j < NCLS; j++) s += __expf(v[j] - m);
    float ls = logf(s) + m;
#pragma unroll
    for (int j = 0; j < NCLS; j++) out[r * NCLS + j] = v[j] - ls;
}

// ---------------- launcher ----------------

extern "C" void kernel_launch(void* const* d_in, const int* in_sizes, int n_in,
                              void* d_out, int out_size, void* d_ws, size_t ws_size,
                              hipStream_t stream) {
    const float* x   = (const float*)d_in[0];
    const int*   ei  = (const int*)d_in[1];
    const float* W1  = (const float*)d_in[2];
    const float* b1  = (const float*)d_in[3];
    const float* W2  = (const float*)d_in[4];
    const float* b2  = (const float*)d_in[5];
    float* out = (float*)d_out;

    const int* row = ei;             // edge_index[0]
    const int* col = ei + N_EDGES;   // edge_index[1]

    // workspace layout (floats)
    float* w = (float*)d_ws;
    float* dinv = w;                                   // N_NODES
    float* norm = dinv + N_NODES;                      // N_EDGES
    float* hA   = norm + N_EDGES;                      // N_NODES*64
    float* hB   = hA + (size_t)N_NODES * HID;          // N_NODES*64
    float* out1 = hB + (size_t)N_NODES * HID;          // N_NODES*64

    const int TB = 256;

    // --- norm precompute ---
    hipMemsetAsync(dinv, 0, N_NODES * sizeof(float), stream);
    deg_kernel<<<(N_EDGES + TB - 1) / TB, TB, 0, stream>>>(col, dinv, N_EDGES);
    dinv_kernel<<<(N_NODES + TB - 1) / TB, TB, 0, stream>>>(dinv, N_NODES);
    norm_kernel<<<(N_EDGES + TB - 1) / TB, TB, 0, stream>>>(row, col, dinv, norm, N_EDGES);

    // --- layer 1: out1 = sum_k (A^k x) W1[k] + b1 ---
    const int W1s = FEAT * HID;  // per-hop weight block
    dim3 db1(HID, 4);
    int dg1 = (N_NODES + 3) / 4;

    dense_kernel<FEAT, HID, HID, 4><<<dg1, db1, 0, stream>>>(x, W1, b1, out1, N_NODES, 0);

    hipMemsetAsync(hB, 0, (size_t)N_NODES * FEAT * sizeof(float), stream);
    hop_kernel<FEAT, 5><<<(N_EDGES * FEAT + TB - 1) / TB, TB, 0, stream>>>(row, col, norm, x, hB, N_EDGES);
    dense_kernel<FEAT, HID, HID, 4><<<dg1, db1, 0, stream>>>(hB, W1 + W1s, nullptr, out1, N_NODES, 1);

    hipMemsetAsync(hA, 0, (size_t)N_NODES * FEAT * sizeof(float), stream);
    hop_kernel<FEAT, 5><<<(N_EDGES * FEAT + TB - 1) / TB, TB, 0, stream>>>(row, col, norm, hB, hA, N_EDGES);
    dense_kernel<FEAT, HID, HID, 4><<<dg1, db1, 0, stream>>>(hA, W1 + 2 * W1s, nullptr, out1, N_NODES, 1);

    hipMemsetAsync(hB, 0, (size_t)N_NODES * FEAT * sizeof(float), stream);
    hop_kernel<FEAT, 5><<<(N_EDGES * FEAT + TB - 1) / TB, TB, 0, stream>>>(row, col, norm, hA, hB, N_EDGES);
    dense_kernel<FEAT, HID, HID, 4><<<dg1, db1, 0, stream>>>(hB, W1 + 3 * W1s, nullptr, out1, N_NODES, 1);

    // relu -> hA (64-wide)
    relu_kernel<<<((size_t)N_NODES * HID + TB - 1) / TB, TB, 0, stream>>>(out1, hA, N_NODES * HID);

    // --- layer 2: out = sum_k (A^k hA) W2[k] + b2 ---
    const int W2s = HID * NCLS;
    dim3 db2(16, 16);
    int dg2 = (N_NODES + 15) / 16;

    dense_kernel<HID, NCLS, 16, 16><<<dg2, db2, 0, stream>>>(hA, W2, b2, out, N_NODES, 0);

    hipMemsetAsync(hB, 0, (size_t)N_NODES * HID * sizeof(float), stream);
    hop_kernel<HID, 6><<<((size_t)N_EDGES * HID + TB - 1) / TB, TB, 0, stream>>>(row, col, norm, hA, hB, N_EDGES);
    dense_kernel<HID, NCLS, 16, 16><<<dg2, db2, 0, stream>>>(hB, W2 + W2s, nullptr, out, N_NODES, 1);

    hipMemsetAsync(hA, 0, (size_t)N_NODES * HID * sizeof(float), stream);
    hop_kernel<HID, 6><<<((size_t)N_EDGES * HID + TB - 1) / TB, TB, 0, stream>>>(row, col, norm, hB, hA, N_EDGES);
    dense_kernel<HID, NCLS, 16, 16><<<dg2, db2, 0, stream>>>(hA, W2 + 2 * W2s, nullptr, out, N_NODES, 1);

    hipMemsetAsync(hB, 0, (size_t)N_NODES * HID * sizeof(float), stream);
    hop_kernel<HID, 6><<<((size_t)N_EDGES * HID + TB - 1) / TB, TB, 0, stream>>>(row, col, norm, hA, hB, N_EDGES);
    dense_kernel<HID, NCLS, 16, 16><<<dg2, db2, 0, stream>>>(hB, W2 + 3 * W2s, nullptr, out, N_NODES, 1);

    // --- log_softmax in place on d_out ---
    lsm_kernel<<<(N_NODES + TB - 1) / TB, TB, 0, stream>>>(out, N_NODES);
}

// Round 2
// 660.029 us; speedup vs baseline: 2.8382x; 2.8382x over previous
//
#include <hip/hip_runtime.h>

#define N_NODES 100000
#define N_EDGES 1600000
#define FEAT 32
#define HID 64
#define NCLS 10
#define NB_SCAN 391  // ceil(100000/256)

// ---------------- CSR build ----------------

__global__ void hist_kernel(const int* __restrict__ col, int* __restrict__ degi, int nE) {
    int e = blockIdx.x * blockDim.x + threadIdx.x;
    if (e < nE) atomicAdd(&degi[col[e]], 1);
}

__global__ void dinv_kernel(const int* __restrict__ degi, float* __restrict__ dinv, int n) {
    int i = blockIdx.x * blockDim.x + threadIdx.x;
    if (i < n) {
        int d = degi[i];
        dinv[i] = (d > 0) ? rsqrtf((float)d) : 0.0f;
    }
}

__global__ void scanA_kernel(const int* __restrict__ degi, int* __restrict__ rowptr,
                             int* __restrict__ bsum, int n) {
    __shared__ int s[256];
    int gid = blockIdx.x * 256 + threadIdx.x;
    int v = (gid < n) ? degi[gid] : 0;
    s[threadIdx.x] = v;
    __syncthreads();
    for (int off = 1; off < 256; off <<= 1) {
        int t = (threadIdx.x >= off) ? s[threadIdx.x - off] : 0;
        __syncthreads();
        s[threadIdx.x] += t;
        __syncthreads();
    }
    if (gid < n) rowptr[gid] = s[threadIdx.x] - v;  // exclusive
    if (threadIdx.x == 255) bsum[blockIdx.x] = s[255];
}

__global__ void scanB_kernel(int* __restrict__ bsum, int nb) {
    __shared__ int s[512];
    int v = (threadIdx.x < nb) ? bsum[threadIdx.x] : 0;
    s[threadIdx.x] = v;
    __syncthreads();
    for (int off = 1; off < 512; off <<= 1) {
        int t = (threadIdx.x >= off) ? s[threadIdx.x - off] : 0;
        __syncthreads();
        s[threadIdx.x] += t;
        __syncthreads();
    }
    if (threadIdx.x < nb) bsum[threadIdx.x] = s[threadIdx.x] - v;  // exclusive
}

__global__ void scanC_kernel(int* __restrict__ rowptr, const int* __restrict__ bsum,
                             int* __restrict__ cnt, int n, int nE) {
    int gid = blockIdx.x * 256 + threadIdx.x;
    if (gid < n) {
        int v = rowptr[gid] + bsum[blockIdx.x];
        rowptr[gid] = v;
        cnt[gid] = v;
    }
    if (gid == 0) rowptr[n] = nE;
}

__global__ void scatter_kernel(const int* __restrict__ row, const int* __restrict__ col,
                               const float* __restrict__ dinv, int* __restrict__ cnt,
                               int2* __restrict__ epk, int nE) {
    int e = blockIdx.x * blockDim.x + threadIdx.x;
    if (e >= nE) return;
    int c = col[e];
    int r = row[e];
    int pos = atomicAdd(&cnt[c], 1);
    int2 v;
    v.x = r;
    v.y = __float_as_int(dinv[r] * dinv[c]);
    epk[pos] = v;
}

// ---------------- CSR gather hops ----------------

// dst[n][0..31] = sum_{e in CSR[n]} w_e * src[idx_e][0..31]
__global__ void gather32_kernel(const int* __restrict__ rowptr, const int2* __restrict__ epk,
                                const float* __restrict__ src, float* __restrict__ dst) {
    int node = (blockIdx.x * blockDim.x + threadIdx.x) >> 6;
    if (node >= N_NODES) return;
    int lane = threadIdx.x & 63;
    int f = lane & 31;
    int g = lane >> 5;  // 2 edge groups
    int s = rowptr[node], e = rowptr[node + 1];
    float acc = 0.0f;
    for (int i = s + g; i < e; i += 2) {
        int2 v = epk[i];
        acc += __int_as_float(v.y) * src[(size_t)v.x * FEAT + f];
    }
    acc += __shfl_xor(acc, 32);
    if (lane < 32) dst[(size_t)node * FEAT + f] = acc;
}

// dst[n][0..15] = (add ? add[n][..] : 0) + sum_e w_e * src[idx_e][0..15]  (16-wide padded)
__global__ void gather16_kernel(const int* __restrict__ rowptr, const int2* __restrict__ epk,
                                const float* __restrict__ src, const float* __restrict__ add,
                                float* __restrict__ dst) {
    int node = (blockIdx.x * blockDim.x + threadIdx.x) >> 6;
    if (node >= N_NODES) return;
    int lane = threadIdx.x & 63;
    int f = lane & 15;
    int g = lane >> 4;  // 4 edge groups
    int s = rowptr[node], e = rowptr[node + 1];
    float acc = 0.0f;
    for (int i = s + g; i < e; i += 4) {
        int2 v = epk[i];
        acc += __int_as_float(v.y) * src[(size_t)v.x * 16 + f];
    }
    acc += __shfl_xor(acc, 16);
    acc += __shfl_xor(acc, 32);
    if (lane < 16) {
        float base = add ? add[(size_t)node * 16 + f] : 0.0f;
        dst[(size_t)node * 16 + f] = base + acc;
    }
}

// ---------------- fused dense layer 1: h = relu([x|p1|p2|p3] @ W1stack + b1) ----------------

__global__ void dense1_kernel(const float* __restrict__ x, const float* __restrict__ p1,
                              const float* __restrict__ p2, const float* __restrict__ p3,
                              const float* __restrict__ W1, const float* __restrict__ b1,
                              float* __restrict__ h, int n) {
    __shared__ float Ws[128 * 64];   // 32KB: stacked (k,c) row-major, k=0..127
    __shared__ float Hs[16][128];    // 8KB
    int tx = threadIdx.x;  // 0..63 (col)
    int ty = threadIdx.y;  // 0..3
    int tid = ty * 64 + tx;

    for (int i = tid; i < 128 * 64; i += 256) Ws[i] = W1[i];

    int row0 = blockIdx.x * 16;
    for (int i = tid; i < 16 * 128; i += 256) {
        int rr = i >> 7;
        int kk = i & 127;
        int r = row0 + rr;
        float val = 0.0f;
        if (r < n) {
            int blk = kk >> 5;
            int kf = kk & 31;
            const float* sp = (blk == 0) ? x : (blk == 1) ? p1 : (blk == 2) ? p2 : p3;
            val = sp[(size_t)r * FEAT + kf];
        }
        Hs[rr][kk] = val;
    }
    __syncthreads();

    float a0 = 0.f, a1 = 0.f, a2 = 0.f, a3 = 0.f;
#pragma unroll 8
    for (int k = 0; k < 128; k++) {
        float wv = Ws[k * 64 + tx];
        a0 += Hs[ty][k] * wv;
        a1 += Hs[ty + 4][k] * wv;
        a2 += Hs[ty + 8][k] * wv;
        a3 += Hs[ty + 12][k] * wv;
    }
    float bb = b1[tx];
    int r;
    r = row0 + ty;      if (r < n) h[(size_t)r * HID + tx] = fmaxf(a0 + bb, 0.f);
    r = row0 + ty + 4;  if (r < n) h[(size_t)r * HID + tx] = fmaxf(a1 + bb, 0.f);
    r = row0 + ty + 8;  if (r < n) h[(size_t)r * HID + tx] = fmaxf(a2 + bb, 0.f);
    r = row0 + ty + 12; if (r < n) h[(size_t)r * HID + tx] = fmaxf(a3 + bb, 0.f);
}

// ---------------- fused dense layer 2 projection: z_k = h @ W2[k] (+b2 for k=0), padded 16 ----------------

#define W2PAD 1032  // 64*16 + 8 : bank-shift per k

__global__ void zgemm_kernel(const float* __restrict__ h, const float* __restrict__ W2,
                             const float* __restrict__ b2, float* __restrict__ zbase,
                             int zstride, int n) {
    __shared__ float Ws[4 * W2PAD];  // ~16.5KB
    __shared__ float Hs[16][64];     // 4KB
    int tx = threadIdx.x;  // 0..63 -> (k, j)
    int ty = threadIdx.y;  // 0..3
    int tid = ty * 64 + tx;

    for (int i = tid; i < 4 * 64 * 16; i += 256) {
        int k = i >> 10;
        int rem = i & 1023;
        int kk = rem >> 4;
        int j = rem & 15;
        Ws[k * W2PAD + kk * 16 + j] = (j < NCLS) ? W2[((size_t)k * HID + kk) * NCLS + j] : 0.0f;
    }

    int row0 = blockIdx.x * 16;
    for (int i = tid; i < 16 * 64; i += 256) {
        int rr = i >> 6;
        int kk = i & 63;
        int r = row0 + rr;
        Hs[rr][kk] = (r < n) ? h[(size_t)r * HID + kk] : 0.0f;
    }
    __syncthreads();

    int k = tx >> 4;
    int j = tx & 15;
    float a0 = 0.f, a1 = 0.f, a2 = 0.f, a3 = 0.f;
#pragma unroll 8
    for (int kk = 0; kk < 64; kk++) {
        float wv = Ws[k * W2PAD + kk * 16 + j];
        a0 += Hs[ty][kk] * wv;
        a1 += Hs[ty + 4][kk] * wv;
        a2 += Hs[ty + 8][kk] * wv;
        a3 += Hs[ty + 12][kk] * wv;
    }
    float bb = (k == 0 && j < NCLS) ? b2[j] : 0.0f;
    if (j >= NCLS) { a0 = a1 = a2 = a3 = 0.f; bb = 0.f; }
    float* zk = zbase + (size_t)k * zstride;
    int r;
    r = row0 + ty;      if (r < n) zk[(size_t)r * 16 + j] = a0 + bb;
    r = row0 + ty + 4;  if (r < n) zk[(size_t)r * 16 + j] = a1 + bb;
    r = row0 + ty + 8;  if (r < n) zk[(size_t)r * 16 + j] = a2 + bb;
    r = row0 + ty + 12; if (r < n) zk[(size_t)r * 16 + j] = a3 + bb;
}

// ---------------- log-softmax: padded-16 input -> 10-wide output ----------------

__global__ void lsm_kernel(const float* __restrict__ t, float* __restrict__ out, int n) {
    int r = blockIdx.x * blockDim.x + threadIdx.x;
    if (r >= n) return;
    float v[NCLS];
    float m = -1e30f;
#pragma unroll
    for (int j = 0; j < NCLS; j++) {
        v[j] = t[(size_t)r * 16 + j];
        m = fmaxf(m, v[j]);
    }
    float s = 0.0f;
#pragma unroll
    for (int j = 0; j < NCLS; j++) s += __expf(v[j] - m);
    float ls = logf(s) + m;
#pragma unroll
    for (int j = 0; j < NCLS; j++) out[(size_t)r * NCLS + j] = v[j] - ls;
}

// ---------------- launcher ----------------

extern "C" void kernel_launch(void* const* d_in, const int* in_sizes, int n_in,
                              void* d_out, int out_size, void* d_ws, size_t ws_size,
                              hipStream_t stream) {
    const float* x  = (const float*)d_in[0];
    const int*   ei = (const int*)d_in[1];
    const float* W1 = (const float*)d_in[2];
    const float* b1 = (const float*)d_in[3];
    const float* W2 = (const float*)d_in[4];
    const float* b2 = (const float*)d_in[5];
    float* out = (float*)d_out;

    const int* row = ei;
    const int* col = ei + N_EDGES;

    // workspace layout (floats, 64-elem aligned)
    float* w = (float*)d_ws;
    size_t o = 0;
    auto alloc = [&](size_t nel) { float* p = w + o; o += (nel + 63) & ~(size_t)63; return p; };

    int*   degi   = (int*)alloc(N_NODES);
    int*   rowptr = (int*)alloc(N_NODES + 1);
    int*   cnt    = (int*)alloc(N_NODES);
    int*   bsum   = (int*)alloc(512);
    float* dinv   = alloc(N_NODES);
    int2*  epk    = (int2*)alloc((size_t)N_EDGES * 2);  // packed (idx, norm)
    float* uni    = alloc((size_t)N_NODES * 32 * 3);    // union: p1..p3 | z0..z3,tA,tB
    float* h      = alloc((size_t)N_NODES * HID);

    float* p1 = uni;
    float* p2 = uni + (size_t)N_NODES * 32;
    float* p3 = uni + (size_t)N_NODES * 64;
    const int ZS = N_NODES * 16;  // z stride (elements)
    float* z0 = uni;              // aliases p region (p dead after dense1)
    float* z1 = uni + ZS;
    float* z2 = uni + 2 * (size_t)ZS;
    float* z3 = uni + 3 * (size_t)ZS;
    float* tA = uni + 4 * (size_t)ZS;
    float* tB = uni + 5 * (size_t)ZS;

    const int TB = 256;
    const int gE = (N_EDGES + TB - 1) / TB;
    const int gN = NB_SCAN;             // 391 blocks for node-parallel
    const int gW = (N_NODES * 64 + TB - 1) / TB;  // one wave per node

    // --- CSR build ---
    hipMemsetAsync(degi, 0, N_NODES * sizeof(int), stream);
    hist_kernel<<<gE, TB, 0, stream>>>(col, degi, N_EDGES);
    dinv_kernel<<<gN, TB, 0, stream>>>(degi, dinv, N_NODES);
    scanA_kernel<<<gN, TB, 0, stream>>>(degi, rowptr, bsum, N_NODES);
    scanB_kernel<<<1, 512, 0, stream>>>(bsum, NB_SCAN);
    scanC_kernel<<<gN, TB, 0, stream>>>(rowptr, bsum, cnt, N_NODES, N_EDGES);
    scatter_kernel<<<gE, TB, 0, stream>>>(row, col, dinv, cnt, epk, N_EDGES);

    // --- layer 1: propagate x at width 32, then fused dense + relu ---
    gather32_kernel<<<gW, TB, 0, stream>>>(rowptr, epk, x, p1);
    gather32_kernel<<<gW, TB, 0, stream>>>(rowptr, epk, p1, p2);
    gather32_kernel<<<gW, TB, 0, stream>>>(rowptr, epk, p2, p3);

    dim3 db(64, 4);
    int gD = (N_NODES + 15) / 16;
    dense1_kernel<<<gD, db, 0, stream>>>(x, p1, p2, p3, W1, b1, h, N_NODES);

    // --- layer 2: project first (z_k = h @ W2[k]), then Horner at width 16 ---
    zgemm_kernel<<<gD, db, 0, stream>>>(h, W2, b2, z0, ZS, N_NODES);

    gather16_kernel<<<gW, TB, 0, stream>>>(rowptr, epk, z3, z2, tA);  // tA = z2 + A z3
    gather16_kernel<<<gW, TB, 0, stream>>>(rowptr, epk, tA, z1, tB);  // tB = z1 + A tA
    gather16_kernel<<<gW, TB, 0, stream>>>(rowptr, epk, tB, z0, tA);  // tA = z0 + A tB

    lsm_kernel<<<gN, TB, 0, stream>>>(tA, out, N_NODES);
}

// Round 3
// 606.353 us; speedup vs baseline: 3.0894x; 1.0885x over previous
//
#include <hip/hip_runtime.h>

#define N_NODES 100000
#define N_EDGES 1600000
#define FEAT 32
#define HID 64
#define NCLS 10
#define NB_SCAN 391   // ceil(100000/256)
#define NPART 8
#define PART_SZ 12500  // N_NODES / NPART
#define NCHUNK 64
#define CHUNK_E 25000  // N_EDGES / NCHUNK

// ---------------- CSR build (XCD-partitioned) ----------------

__global__ void hist_kernel(const int* __restrict__ col, int* __restrict__ degi) {
    int part = blockIdx.x & (NPART - 1);
    int chunk = blockIdx.x / NPART;
    int lo = part * PART_SZ, hi = lo + PART_SZ;
    int e0 = chunk * CHUNK_E;
    for (int e = e0 + threadIdx.x; e < e0 + CHUNK_E; e += 256) {
        int c = col[e];
        if (c >= lo && c < hi) atomicAdd(&degi[c], 1);
    }
}

__global__ void dinv_kernel(const int* __restrict__ degi, float* __restrict__ dinv, int n) {
    int i = blockIdx.x * blockDim.x + threadIdx.x;
    if (i < n) {
        int d = degi[i];
        dinv[i] = (d > 0) ? rsqrtf((float)d) : 0.0f;
    }
}

__global__ void scanA_kernel(const int* __restrict__ degi, int* __restrict__ rowptr,
                             int* __restrict__ bsum, int n) {
    __shared__ int s[256];
    int gid = blockIdx.x * 256 + threadIdx.x;
    int v = (gid < n) ? degi[gid] : 0;
    s[threadIdx.x] = v;
    __syncthreads();
    for (int off = 1; off < 256; off <<= 1) {
        int t = (threadIdx.x >= off) ? s[threadIdx.x - off] : 0;
        __syncthreads();
        s[threadIdx.x] += t;
        __syncthreads();
    }
    if (gid < n) rowptr[gid] = s[threadIdx.x] - v;  // exclusive
    if (threadIdx.x == 255) bsum[blockIdx.x] = s[255];
}

__global__ void scanB_kernel(int* __restrict__ bsum, int nb) {
    __shared__ int s[512];
    int v = (threadIdx.x < nb) ? bsum[threadIdx.x] : 0;
    s[threadIdx.x] = v;
    __syncthreads();
    for (int off = 1; off < 512; off <<= 1) {
        int t = (threadIdx.x >= off) ? s[threadIdx.x - off] : 0;
        __syncthreads();
        s[threadIdx.x] += t;
        __syncthreads();
    }
    if (threadIdx.x < nb) bsum[threadIdx.x] = s[threadIdx.x] - v;  // exclusive
}

// writes final rowptr and initializes cnt (aliased onto degi by caller)
__global__ void scanC_kernel(int* __restrict__ rowptr, const int* __restrict__ bsum,
                             int* __restrict__ cnt, int n, int nE) {
    int gid = blockIdx.x * 256 + threadIdx.x;
    if (gid < n) {
        int v = rowptr[gid] + bsum[blockIdx.x];
        rowptr[gid] = v;
        cnt[gid] = v;
    }
    if (gid == 0) rowptr[n] = nE;
}

__global__ void scatter_kernel(const int* __restrict__ row, const int* __restrict__ col,
                               int* __restrict__ cnt, int* __restrict__ eidx) {
    int part = blockIdx.x & (NPART - 1);
    int chunk = blockIdx.x / NPART;
    int lo = part * PART_SZ, hi = lo + PART_SZ;
    int e0 = chunk * CHUNK_E;
    for (int e = e0 + threadIdx.x; e < e0 + CHUNK_E; e += 256) {
        int c = col[e];
        int r = row[e];
        if (c >= lo && c < hi) {
            int pos = atomicAdd(&cnt[c], 1);
            eidx[pos] = r;
        }
    }
}

// ---------------- prescale: t0 = dinv * x ----------------

__global__ void prescale_kernel(const float* __restrict__ x, const float* __restrict__ dinv,
                                float* __restrict__ t0) {
    int i = blockIdx.x * 256 + threadIdx.x;
    if (i < N_NODES * FEAT) t0[i] = x[i] * dinv[i >> 5];
}

// ---------------- gather hops (CSR, idx-only payload) ----------------

// p[c] = dinv[c] * sum_{e in CSR[c]} src[idx_e][f]   (src is pre-scaled)
// if WP: pre[c] = dinv[c] * p[c]
template <int WP>
__global__ void gather32_kernel(const int* __restrict__ rowptr, const int* __restrict__ eidx,
                                const float* __restrict__ dinv, const float* __restrict__ src,
                                float* __restrict__ pout, float* __restrict__ preout) {
    int node = (blockIdx.x * blockDim.x + threadIdx.x) >> 6;
    if (node >= N_NODES) return;
    int lane = threadIdx.x & 63;
    int f = lane & 31;
    int g = lane >> 5;  // 2 groups
    int s = rowptr[node], e = rowptr[node + 1];
    float acc = 0.0f;
    int base = (s & ~3) + g * 4;
    for (int b = base; b < e; b += 8) {
        int4 q = *(const int4*)(eidx + b);  // 16B-aligned
        float v0 = (b     >= s && b     < e) ? src[(size_t)q.x * FEAT + f] : 0.0f;
        float v1 = (b + 1 >= s && b + 1 < e) ? src[(size_t)q.y * FEAT + f] : 0.0f;
        float v2 = (b + 2 >= s && b + 2 < e) ? src[(size_t)q.z * FEAT + f] : 0.0f;
        float v3 = (b + 3 >= s && b + 3 < e) ? src[(size_t)q.w * FEAT + f] : 0.0f;
        acc += v0 + v1 + v2 + v3;
    }
    acc += __shfl_xor(acc, 32);
    if (lane < 32) {
        float dv = dinv[node];
        float p = dv * acc;
        pout[(size_t)node * FEAT + f] = p;
        if (WP) preout[(size_t)node * FEAT + f] = dv * p;
    }
}

// Horner step at width 16 (padded):
//   v[c] = add[c] + dinv[c] * sum src[idx_e][f]
//   FINAL=0: out[c] = dinv[c]*v[c] (pre-scaled for next hop)
//   FINAL=1: out = log_softmax(v) over f<10, written 10-wide
template <int FINAL>
__global__ void gather16_kernel(const int* __restrict__ rowptr, const int* __restrict__ eidx,
                                const float* __restrict__ dinv, const float* __restrict__ src,
                                const float* __restrict__ add, float* __restrict__ outv) {
    int node = (blockIdx.x * blockDim.x + threadIdx.x) >> 6;
    if (node >= N_NODES) return;
    int lane = threadIdx.x & 63;
    int f = lane & 15;
    int g = lane >> 4;  // 4 groups
    int s = rowptr[node], e = rowptr[node + 1];
    float acc = 0.0f;
    int base = (s & ~3) + g * 4;
    for (int b = base; b < e; b += 16) {
        int4 q = *(const int4*)(eidx + b);
        float v0 = (b     >= s && b     < e) ? src[(size_t)q.x * 16 + f] : 0.0f;
        float v1 = (b + 1 >= s && b + 1 < e) ? src[(size_t)q.y * 16 + f] : 0.0f;
        float v2 = (b + 2 >= s && b + 2 < e) ? src[(size_t)q.z * 16 + f] : 0.0f;
        float v3 = (b + 3 >= s && b + 3 < e) ? src[(size_t)q.w * 16 + f] : 0.0f;
        acc += v0 + v1 + v2 + v3;
    }
    acc += __shfl_xor(acc, 16);
    acc += __shfl_xor(acc, 32);
    float dv = dinv[node];
    float v = add[(size_t)node * 16 + f] + dv * acc;
    if (!FINAL) {
        if (lane < 16) outv[(size_t)node * 16 + f] = dv * v;
    } else {
        float l = (f < NCLS) ? v : -1e30f;
        float m = l;
        m = fmaxf(m, __shfl_xor(m, 1));
        m = fmaxf(m, __shfl_xor(m, 2));
        m = fmaxf(m, __shfl_xor(m, 4));
        m = fmaxf(m, __shfl_xor(m, 8));
        float ex = (f < NCLS) ? __expf(l - m) : 0.0f;
        ex += __shfl_xor(ex, 1);
        ex += __shfl_xor(ex, 2);
        ex += __shfl_xor(ex, 4);
        ex += __shfl_xor(ex, 8);
        float ls = logf(ex) + m;
        if (lane < 16 && f < NCLS) outv[(size_t)node * NCLS + f] = l - ls;
    }
}

// ---------------- fused dense layer 1: h = relu([x|p1|p2|p3] @ W1stack + b1) ----------------

__global__ void dense1_kernel(const float* __restrict__ x, const float* __restrict__ p1,
                              const float* __restrict__ p2, const float* __restrict__ p3,
                              const float* __restrict__ W1, const float* __restrict__ b1,
                              float* __restrict__ h, int n) {
    __shared__ float Ws[128 * 64];
    __shared__ float Hs[16][128];
    int tx = threadIdx.x;  // 0..63 (col)
    int ty = threadIdx.y;  // 0..3
    int tid = ty * 64 + tx;

    for (int i = tid; i < 128 * 64; i += 256) Ws[i] = W1[i];

    int row0 = blockIdx.x * 16;
    for (int i = tid; i < 16 * 128; i += 256) {
        int rr = i >> 7;
        int kk = i & 127;
        int r = row0 + rr;
        float val = 0.0f;
        if (r < n) {
            int blk = kk >> 5;
            int kf = kk & 31;
            const float* sp = (blk == 0) ? x : (blk == 1) ? p1 : (blk == 2) ? p2 : p3;
            val = sp[(size_t)r * FEAT + kf];
        }
        Hs[rr][kk] = val;
    }
    __syncthreads();

    float a0 = 0.f, a1 = 0.f, a2 = 0.f, a3 = 0.f;
#pragma unroll 8
    for (int k = 0; k < 128; k++) {
        float wv = Ws[k * 64 + tx];
        a0 += Hs[ty][k] * wv;
        a1 += Hs[ty + 4][k] * wv;
        a2 += Hs[ty + 8][k] * wv;
        a3 += Hs[ty + 12][k] * wv;
    }
    float bb = b1[tx];
    int r;
    r = row0 + ty;      if (r < n) h[(size_t)r * HID + tx] = fmaxf(a0 + bb, 0.f);
    r = row0 + ty + 4;  if (r < n) h[(size_t)r * HID + tx] = fmaxf(a1 + bb, 0.f);
    r = row0 + ty + 8;  if (r < n) h[(size_t)r * HID + tx] = fmaxf(a2 + bb, 0.f);
    r = row0 + ty + 12; if (r < n) h[(size_t)r * HID + tx] = fmaxf(a3 + bb, 0.f);
}

// ---------------- layer-2 projection: z_k = h @ W2[k] (+b2 on k=0; k=3 pre-scaled) ----------------

#define W2PAD 1032  // 64*16 + 8

__global__ void zgemm_kernel(const float* __restrict__ h, const float* __restrict__ W2,
                             const float* __restrict__ b2, const float* __restrict__ dinv,
                             float* __restrict__ zbase, int zstride, int n) {
    __shared__ float Ws[4 * W2PAD];
    __shared__ float Hs[16][64];
    int tx = threadIdx.x;
    int ty = threadIdx.y;
    int tid = ty * 64 + tx;

    for (int i = tid; i < 4 * 64 * 16; i += 256) {
        int k = i >> 10;
        int rem = i & 1023;
        int kk = rem >> 4;
        int j = rem & 15;
        Ws[k * W2PAD + kk * 16 + j] = (j < NCLS) ? W2[((size_t)k * HID + kk) * NCLS + j] : 0.0f;
    }

    int row0 = blockIdx.x * 16;
    for (int i = tid; i < 16 * 64; i += 256) {
        int rr = i >> 6;
        int kk = i & 63;
        int r = row0 + rr;
        Hs[rr][kk] = (r < n) ? h[(size_t)r * HID + kk] : 0.0f;
    }
    __syncthreads();

    int k = tx >> 4;
    int j = tx & 15;
    float a0 = 0.f, a1 = 0.f, a2 = 0.f, a3 = 0.f;
#pragma unroll 8
    for (int kk = 0; kk < 64; kk++) {
        float wv = Ws[k * W2PAD + kk * 16 + j];
        a0 += Hs[ty][kk] * wv;
        a1 += Hs[ty + 4][kk] * wv;
        a2 += Hs[ty + 8][kk] * wv;
        a3 += Hs[ty + 12][kk] * wv;
    }
    float bb = (k == 0 && j < NCLS) ? b2[j] : 0.0f;
    if (j >= NCLS) { a0 = a1 = a2 = a3 = 0.f; bb = 0.f; }
    float* zk = zbase + (size_t)k * zstride;
    int r;
    r = row0 + ty;      if (r < n) { float sc = (k == 3) ? dinv[r] : 1.0f; zk[(size_t)r * 16 + j] = (a0 + bb) * sc; }
    r = row0 + ty + 4;  if (r < n) { float sc = (k == 3) ? dinv[r] : 1.0f; zk[(size_t)r * 16 + j] = (a1 + bb) * sc; }
    r = row0 + ty + 8;  if (r < n) { float sc = (k == 3) ? dinv[r] : 1.0f; zk[(size_t)r * 16 + j] = (a2 + bb) * sc; }
    r = row0 + ty + 12; if (r < n) { float sc = (k == 3) ? dinv[r] : 1.0f; zk[(size_t)r * 16 + j] = (a3 + bb) * sc; }
}

// ---------------- launcher ----------------

extern "C" void kernel_launch(void* const* d_in, const int* in_sizes, int n_in,
                              void* d_out, int out_size, void* d_ws, size_t ws_size,
                              hipStream_t stream) {
    const float* x  = (const float*)d_in[0];
    const int*   ei = (const int*)d_in[1];
    const float* W1 = (const float*)d_in[2];
    const float* b1 = (const float*)d_in[3];
    const float* W2 = (const float*)d_in[4];
    const float* b2 = (const float*)d_in[5];
    float* out = (float*)d_out;

    const int* row = ei;
    const int* col = ei + N_EDGES;

    // workspace layout (floats, 256B-aligned chunks)
    float* w = (float*)d_ws;
    size_t o = 0;
    auto alloc = [&](size_t nel) { float* p = w + o; o += (nel + 63) & ~(size_t)63; return p; };

    int*   degi   = (int*)alloc(N_NODES);       // also reused as cnt
    int*   rowptr = (int*)alloc(N_NODES + 1);
    int*   bsum   = (int*)alloc(512);
    float* dinv   = alloc(N_NODES);
    int*   eidx   = (int*)alloc(N_EDGES + 16);  // idx-only CSR payload (+pad)
    float* bufA   = alloc((size_t)N_NODES * 32);
    float* bufB   = alloc((size_t)N_NODES * 32);
    float* bufC   = alloc((size_t)N_NODES * 32);
    float* bufD   = alloc((size_t)N_NODES * 32);
    float* h      = alloc((size_t)N_NODES * HID);

    // layer-1 buffer roles
    float* t0  = bufA;  // prescaled x; dead after hop1
    float* p1  = bufB;
    float* p1p = bufC;  // dead after hop2
    float* p2  = bufD;
    float* p2p = bufA;  // reuse A (t0 dead)
    float* p3  = bufC;  // reuse C (p1p dead)
    // layer-2 aliases (all layer-1 buffers dead after dense1)
    const int ZS = N_NODES * 16;
    float* z0  = bufA;
    float* z1  = bufA + ZS;
    float* z2  = bufB;
    float* z3p = bufB + ZS;  // pre-scaled by zgemm
    float* tAp = bufC;
    float* tBp = bufC + ZS;

    int* cnt = degi;  // degi dead after scanA; scanC re-inits as cnt

    const int TB = 256;
    const int gN = NB_SCAN;
    const int gW = (N_NODES * 64) / TB;  // 25000: one wave per node

    // --- CSR build ---
    hipMemsetAsync(degi, 0, N_NODES * sizeof(int), stream);
    hist_kernel<<<NCHUNK * NPART, TB, 0, stream>>>(col, degi);
    dinv_kernel<<<gN, TB, 0, stream>>>(degi, dinv, N_NODES);
    scanA_kernel<<<gN, TB, 0, stream>>>(degi, rowptr, bsum, N_NODES);
    scanB_kernel<<<1, 512, 0, stream>>>(bsum, NB_SCAN);
    scanC_kernel<<<gN, TB, 0, stream>>>(rowptr, bsum, cnt, N_NODES, N_EDGES);
    scatter_kernel<<<NCHUNK * NPART, TB, 0, stream>>>(row, col, cnt, eidx);

    // --- layer 1 ---
    prescale_kernel<<<(N_NODES * FEAT + TB - 1) / TB, TB, 0, stream>>>(x, dinv, t0);
    gather32_kernel<1><<<gW, TB, 0, stream>>>(rowptr, eidx, dinv, t0,  p1, p1p);
    gather32_kernel<1><<<gW, TB, 0, stream>>>(rowptr, eidx, dinv, p1p, p2, p2p);
    gather32_kernel<0><<<gW, TB, 0, stream>>>(rowptr, eidx, dinv, p2p, p3, nullptr);

    dim3 db(64, 4);
    int gD = (N_NODES + 15) / 16;
    dense1_kernel<<<gD, db, 0, stream>>>(x, p1, p2, p3, W1, b1, h, N_NODES);

    // --- layer 2: project to 10-wide first, then Horner at width 16 ---
    zgemm_kernel<<<gD, db, 0, stream>>>(h, W2, b2, dinv, z0, ZS, N_NODES);

    gather16_kernel<0><<<gW, TB, 0, stream>>>(rowptr, eidx, dinv, z3p, z2, tAp);
    gather16_kernel<0><<<gW, TB, 0, stream>>>(rowptr, eidx, dinv, tAp, z1, tBp);
    gather16_kernel<1><<<gW, TB, 0, stream>>>(rowptr, eidx, dinv, tBp, z0, out);
}

// Round 4
// 487.552 us; speedup vs baseline: 3.8422x; 1.2437x over previous
//
#include <hip/hip_runtime.h>

#define N_NODES 100000
#define N_EDGES 1600000
#define FEAT 32
#define HID 64
#define NCLS 10

#define BUCKET_SHIFT 8
#define NBUCKET 391              // ceil(100000 / 256)
#define NCB 256                  // blocks for bucket hist/scatter passes
#define CHUNK ((N_EDGES + NCB - 1) / NCB)   // 6250
#define BH_N (NBUCKET * NCB)     // 100096
#define NB_BH ((BH_N + 255) / 256)          // 391
#define CAP 6144                 // LDS staging capacity per bucket (mean ~4096)

// ---------------- two-level counting sort: CSR build ----------------

__global__ void bucket_hist(const int* __restrict__ col, int* __restrict__ blockhist) {
    __shared__ int lh[NBUCKET];
    int blk = blockIdx.x;
    for (int i = threadIdx.x; i < NBUCKET; i += 256) lh[i] = 0;
    __syncthreads();
    int e0 = blk * CHUNK;
    int e1 = min(e0 + CHUNK, N_EDGES);
    for (int e = e0 + threadIdx.x; e < e1; e += 256)
        atomicAdd(&lh[col[e] >> BUCKET_SHIFT], 1);
    __syncthreads();
    for (int i = threadIdx.x; i < NBUCKET; i += 256)
        blockhist[i * NCB + blk] = lh[i];
}

__global__ void scanA_kernel(const int* __restrict__ src, int* __restrict__ dst,
                             int* __restrict__ bsum, int n) {
    __shared__ int s[256];
    int gid = blockIdx.x * 256 + threadIdx.x;
    int v = (gid < n) ? src[gid] : 0;
    s[threadIdx.x] = v;
    __syncthreads();
    for (int off = 1; off < 256; off <<= 1) {
        int t = (threadIdx.x >= off) ? s[threadIdx.x - off] : 0;
        __syncthreads();
        s[threadIdx.x] += t;
        __syncthreads();
    }
    if (gid < n) dst[gid] = s[threadIdx.x] - v;  // exclusive within block
    if (threadIdx.x == 255) bsum[blockIdx.x] = s[255];
}

__global__ void scanB_kernel(int* __restrict__ bsum, int nb) {
    __shared__ int s[512];
    int v = (threadIdx.x < nb) ? bsum[threadIdx.x] : 0;
    s[threadIdx.x] = v;
    __syncthreads();
    for (int off = 1; off < 512; off <<= 1) {
        int t = (threadIdx.x >= off) ? s[threadIdx.x - off] : 0;
        __syncthreads();
        s[threadIdx.x] += t;
        __syncthreads();
    }
    if (threadIdx.x < nb) bsum[threadIdx.x] = s[threadIdx.x] - v;  // exclusive
}

__global__ void scanC_add(int* __restrict__ dst, const int* __restrict__ bsum, int n) {
    int gid = blockIdx.x * 256 + threadIdx.x;
    if (gid < n) dst[gid] += bsum[blockIdx.x];
}

__global__ void bucket_scatter(const int* __restrict__ row, const int* __restrict__ col,
                               const int* __restrict__ base, int* __restrict__ packed) {
    __shared__ int lcnt[NBUCKET];
    __shared__ int lbase[NBUCKET];
    int blk = blockIdx.x;
    for (int i = threadIdx.x; i < NBUCKET; i += 256) {
        lcnt[i] = 0;
        lbase[i] = base[i * NCB + blk];
    }
    __syncthreads();
    int e0 = blk * CHUNK;
    int e1 = min(e0 + CHUNK, N_EDGES);
    for (int e = e0 + threadIdx.x; e < e1; e += 256) {
        int c = col[e];
        int r = row[e];
        int b = c >> BUCKET_SHIFT;
        int pos = lbase[b] + atomicAdd(&lcnt[b], 1);
        packed[pos] = (r << BUCKET_SHIFT) | (c & 255);
    }
}

// one block per bucket: exact sort within bucket; writes rowptr, dinv, eidx
__global__ void bucket_sort(const int* __restrict__ base, const int* __restrict__ packed,
                            int* __restrict__ rowptr, int* __restrict__ eidx,
                            float* __restrict__ dinv) {
    __shared__ int stage[CAP];
    __shared__ int cnt[256];
    __shared__ int lscan[256];
    int b = blockIdx.x;
    int tid = threadIdx.x;
    int s = base[b * NCB];
    int e = (b == NBUCKET - 1) ? N_EDGES : base[(b + 1) * NCB];
    int m = e - s;
    bool fits = (m <= CAP);
    cnt[tid] = 0;
    __syncthreads();
    for (int i = tid; i < m; i += 256) {
        int p = packed[s + i];
        if (fits) stage[i] = p;
        atomicAdd(&cnt[p & 255], 1);
    }
    __syncthreads();
    int node = (b << BUCKET_SHIFT) + tid;
    int c = cnt[tid];
    if (node < N_NODES) dinv[node] = (c > 0) ? rsqrtf((float)c) : 0.0f;
    // exclusive scan of cnt
    lscan[tid] = c;
    __syncthreads();
    for (int off = 1; off < 256; off <<= 1) {
        int t = (tid >= off) ? lscan[tid - off] : 0;
        __syncthreads();
        lscan[tid] += t;
        __syncthreads();
    }
    int excl = lscan[tid] - c;
    if (node < N_NODES) rowptr[node] = s + excl;
    if (b == NBUCKET - 1 && tid == 0) rowptr[N_NODES] = N_EDGES;
    __syncthreads();
    lscan[tid] = excl;
    cnt[tid] = 0;
    __syncthreads();
    for (int i = tid; i < m; i += 256) {
        int p = fits ? stage[i] : packed[s + i];
        int cl = p & 255;
        int pos = lscan[cl] + atomicAdd(&cnt[cl], 1);
        eidx[s + pos] = p >> BUCKET_SHIFT;
    }
}

// ---------------- prescale: t0 = dinv * x ----------------

__global__ void prescale_kernel(const float* __restrict__ x, const float* __restrict__ dinv,
                                float* __restrict__ t0) {
    int i = blockIdx.x * 256 + threadIdx.x;
    if (i < N_NODES * FEAT) t0[i] = x[i] * dinv[i >> 5];
}

// ---------------- gather hops (CSR, idx-only payload) ----------------

template <int WP>
__global__ void gather32_kernel(const int* __restrict__ rowptr, const int* __restrict__ eidx,
                                const float* __restrict__ dinv, const float* __restrict__ src,
                                float* __restrict__ pout, float* __restrict__ preout) {
    int node = (blockIdx.x * blockDim.x + threadIdx.x) >> 6;
    if (node >= N_NODES) return;
    int lane = threadIdx.x & 63;
    int f = lane & 31;
    int g = lane >> 5;  // 2 groups
    int s = rowptr[node], e = rowptr[node + 1];
    float acc = 0.0f;
    int base = (s & ~3) + g * 4;
    for (int b = base; b < e; b += 8) {
        int4 q = *(const int4*)(eidx + b);  // 16B-aligned
        float v0 = (b     >= s && b     < e) ? src[(size_t)q.x * FEAT + f] : 0.0f;
        float v1 = (b + 1 >= s && b + 1 < e) ? src[(size_t)q.y * FEAT + f] : 0.0f;
        float v2 = (b + 2 >= s && b + 2 < e) ? src[(size_t)q.z * FEAT + f] : 0.0f;
        float v3 = (b + 3 >= s && b + 3 < e) ? src[(size_t)q.w * FEAT + f] : 0.0f;
        acc += v0 + v1 + v2 + v3;
    }
    acc += __shfl_xor(acc, 32);
    if (lane < 32) {
        float dv = dinv[node];
        float p = dv * acc;
        pout[(size_t)node * FEAT + f] = p;
        if (WP) preout[(size_t)node * FEAT + f] = dv * p;
    }
}

template <int FINAL>
__global__ void gather16_kernel(const int* __restrict__ rowptr, const int* __restrict__ eidx,
                                const float* __restrict__ dinv, const float* __restrict__ src,
                                const float* __restrict__ add, float* __restrict__ outv) {
    int node = (blockIdx.x * blockDim.x + threadIdx.x) >> 6;
    if (node >= N_NODES) return;
    int lane = threadIdx.x & 63;
    int f = lane & 15;
    int g = lane >> 4;  // 4 groups
    int s = rowptr[node], e = rowptr[node + 1];
    float acc = 0.0f;
    int base = (s & ~3) + g * 4;
    for (int b = base; b < e; b += 16) {
        int4 q = *(const int4*)(eidx + b);
        float v0 = (b     >= s && b     < e) ? src[(size_t)q.x * 16 + f] : 0.0f;
        float v1 = (b + 1 >= s && b + 1 < e) ? src[(size_t)q.y * 16 + f] : 0.0f;
        float v2 = (b + 2 >= s && b + 2 < e) ? src[(size_t)q.z * 16 + f] : 0.0f;
        float v3 = (b + 3 >= s && b + 3 < e) ? src[(size_t)q.w * 16 + f] : 0.0f;
        acc += v0 + v1 + v2 + v3;
    }
    acc += __shfl_xor(acc, 16);
    acc += __shfl_xor(acc, 32);
    float dv = dinv[node];
    float v = add[(size_t)node * 16 + f] + dv * acc;
    if (!FINAL) {
        if (lane < 16) outv[(size_t)node * 16 + f] = dv * v;
    } else {
        float l = (f < NCLS) ? v : -1e30f;
        float m = l;
        m = fmaxf(m, __shfl_xor(m, 1));
        m = fmaxf(m, __shfl_xor(m, 2));
        m = fmaxf(m, __shfl_xor(m, 4));
        m = fmaxf(m, __shfl_xor(m, 8));
        float ex = (f < NCLS) ? __expf(l - m) : 0.0f;
        ex += __shfl_xor(ex, 1);
        ex += __shfl_xor(ex, 2);
        ex += __shfl_xor(ex, 4);
        ex += __shfl_xor(ex, 8);
        float ls = logf(ex) + m;
        if (lane < 16 && f < NCLS) outv[(size_t)node * NCLS + f] = l - ls;
    }
}

// ---------------- fused dense layer 1: h = relu([x|p1|p2|p3] @ W1stack + b1) ----------------

__global__ void dense1_kernel(const float* __restrict__ x, const float* __restrict__ p1,
                              const float* __restrict__ p2, const float* __restrict__ p3,
                              const float* __restrict__ W1, const float* __restrict__ b1,
                              float* __restrict__ h, int n) {
    __shared__ float Ws[128 * 64];
    __shared__ float Hs[16][128];
    int tx = threadIdx.x;  // 0..63 (col)
    int ty = threadIdx.y;  // 0..3
    int tid = ty * 64 + tx;

    for (int i = tid; i < 128 * 64; i += 256) Ws[i] = W1[i];

    int row0 = blockIdx.x * 16;
    for (int i = tid; i < 16 * 128; i += 256) {
        int rr = i >> 7;
        int kk = i & 127;
        int r = row0 + rr;
        float val = 0.0f;
        if (r < n) {
            int blk = kk >> 5;
            int kf = kk & 31;
            const float* sp = (blk == 0) ? x : (blk == 1) ? p1 : (blk == 2) ? p2 : p3;
            val = sp[(size_t)r * FEAT + kf];
        }
        Hs[rr][kk] = val;
    }
    __syncthreads();

    float a0 = 0.f, a1 = 0.f, a2 = 0.f, a3 = 0.f;
#pragma unroll 8
    for (int k = 0; k < 128; k++) {
        float wv = Ws[k * 64 + tx];
        a0 += Hs[ty][k] * wv;
        a1 += Hs[ty + 4][k] * wv;
        a2 += Hs[ty + 8][k] * wv;
        a3 += Hs[ty + 12][k] * wv;
    }
    float bb = b1[tx];
    int r;
    r = row0 + ty;      if (r < n) h[(size_t)r * HID + tx] = fmaxf(a0 + bb, 0.f);
    r = row0 + ty + 4;  if (r < n) h[(size_t)r * HID + tx] = fmaxf(a1 + bb, 0.f);
    r = row0 + ty + 8;  if (r < n) h[(size_t)r * HID + tx] = fmaxf(a2 + bb, 0.f);
    r = row0 + ty + 12; if (r < n) h[(size_t)r * HID + tx] = fmaxf(a3 + bb, 0.f);
}

// ---------------- layer-2 projection: z_k = h @ W2[k] (+b2 on k=0; k=3 pre-scaled) ----------------

#define W2PAD 1032  // 64*16 + 8

__global__ void zgemm_kernel(const float* __restrict__ h, const float* __restrict__ W2,
                             const float* __restrict__ b2, const float* __restrict__ dinv,
                             float* __restrict__ zbase, int zstride, int n) {
    __shared__ float Ws[4 * W2PAD];
    __shared__ float Hs[16][64];
    int tx = threadIdx.x;
    int ty = threadIdx.y;
    int tid = ty * 64 + tx;

    for (int i = tid; i < 4 * 64 * 16; i += 256) {
        int k = i >> 10;
        int rem = i & 1023;
        int kk = rem >> 4;
        int j = rem & 15;
        Ws[k * W2PAD + kk * 16 + j] = (j < NCLS) ? W2[((size_t)k * HID + kk) * NCLS + j] : 0.0f;
    }

    int row0 = blockIdx.x * 16;
    for (int i = tid; i < 16 * 64; i += 256) {
        int rr = i >> 6;
        int kk = i & 63;
        int r = row0 + rr;
        Hs[rr][kk] = (r < n) ? h[(size_t)r * HID + kk] : 0.0f;
    }
    __syncthreads();

    int k = tx >> 4;
    int j = tx & 15;
    float a0 = 0.f, a1 = 0.f, a2 = 0.f, a3 = 0.f;
#pragma unroll 8
    for (int kk = 0; kk < 64; kk++) {
        float wv = Ws[k * W2PAD + kk * 16 + j];
        a0 += Hs[ty][kk] * wv;
        a1 += Hs[ty + 4][kk] * wv;
        a2 += Hs[ty + 8][kk] * wv;
        a3 += Hs[ty + 12][kk] * wv;
    }
    float bb = (k == 0 && j < NCLS) ? b2[j] : 0.0f;
    if (j >= NCLS) { a0 = a1 = a2 = a3 = 0.f; bb = 0.f; }
    float* zk = zbase + (size_t)k * zstride;
    int r;
    r = row0 + ty;      if (r < n) { float sc = (k == 3) ? dinv[r] : 1.0f; zk[(size_t)r * 16 + j] = (a0 + bb) * sc; }
    r = row0 + ty + 4;  if (r < n) { float sc = (k == 3) ? dinv[r] : 1.0f; zk[(size_t)r * 16 + j] = (a1 + bb) * sc; }
    r = row0 + ty + 8;  if (r < n) { float sc = (k == 3) ? dinv[r] : 1.0f; zk[(size_t)r * 16 + j] = (a2 + bb) * sc; }
    r = row0 + ty + 12; if (r < n) { float sc = (k == 3) ? dinv[r] : 1.0f; zk[(size_t)r * 16 + j] = (a3 + bb) * sc; }
}

// ---------------- launcher ----------------

extern "C" void kernel_launch(void* const* d_in, const int* in_sizes, int n_in,
                              void* d_out, int out_size, void* d_ws, size_t ws_size,
                              hipStream_t stream) {
    const float* x  = (const float*)d_in[0];
    const int*   ei = (const int*)d_in[1];
    const float* W1 = (const float*)d_in[2];
    const float* b1 = (const float*)d_in[3];
    const float* W2 = (const float*)d_in[4];
    const float* b2 = (const float*)d_in[5];
    float* out = (float*)d_out;

    const int* row = ei;
    const int* col = ei + N_EDGES;

    // workspace layout (floats, 256B-aligned chunks)
    float* w = (float*)d_ws;
    size_t o = 0;
    auto alloc = [&](size_t nel) { float* p = w + o; o += (nel + 63) & ~(size_t)63; return p; };

    int*   rowptr = (int*)alloc(N_NODES + 1);
    int*   bsum   = (int*)alloc(512);
    float* dinv   = alloc(N_NODES);
    int*   eidx   = (int*)alloc(N_EDGES + 16);  // idx-only CSR payload (+pad)
    float* bufA   = alloc((size_t)N_NODES * 32);
    float* bufB   = alloc((size_t)N_NODES * 32);
    float* bufC   = alloc((size_t)N_NODES * 32);
    float* bufD   = alloc((size_t)N_NODES * 32);
    float* h      = alloc((size_t)N_NODES * HID);

    // CSR-build temporaries alias later-used buffers (build completes first)
    int* blockhist = (int*)bufB;   // BH_N ints
    int* bhbase    = (int*)bufC;   // BH_N ints
    int* packed    = (int*)h;      // N_EDGES ints

    // layer-1 buffer roles
    float* t0  = bufA;
    float* p1  = bufB;
    float* p1p = bufC;
    float* p2  = bufD;
    float* p2p = bufA;
    float* p3  = bufC;
    // layer-2 aliases
    const int ZS = N_NODES * 16;
    float* z0  = bufA;
    float* z1  = bufA + ZS;
    float* z2  = bufB;
    float* z3p = bufB + ZS;
    float* tAp = bufC;
    float* tBp = bufC + ZS;

    const int TB = 256;
    const int gW = (N_NODES * 64) / TB;  // 25000: one wave per node

    // --- CSR build: two-level counting sort ---
    bucket_hist<<<NCB, TB, 0, stream>>>(col, blockhist);
    scanA_kernel<<<NB_BH, TB, 0, stream>>>(blockhist, bhbase, bsum, BH_N);
    scanB_kernel<<<1, 512, 0, stream>>>(bsum, NB_BH);
    scanC_add<<<NB_BH, TB, 0, stream>>>(bhbase, bsum, BH_N);
    bucket_scatter<<<NCB, TB, 0, stream>>>(row, col, bhbase, packed);
    bucket_sort<<<NBUCKET, TB, 0, stream>>>(bhbase, packed, rowptr, eidx, dinv);

    // --- layer 1 ---
    prescale_kernel<<<(N_NODES * FEAT + TB - 1) / TB, TB, 0, stream>>>(x, dinv, t0);
    gather32_kernel<1><<<gW, TB, 0, stream>>>(rowptr, eidx, dinv, t0,  p1, p1p);
    gather32_kernel<1><<<gW, TB, 0, stream>>>(rowptr, eidx, dinv, p1p, p2, p2p);
    gather32_kernel<0><<<gW, TB, 0, stream>>>(rowptr, eidx, dinv, p2p, p3, nullptr);

    dim3 db(64, 4);
    int gD = (N_NODES + 15) / 16;
    dense1_kernel<<<gD, db, 0, stream>>>(x, p1, p2, p3, W1, b1, h, N_NODES);

    // --- layer 2: project to 10-wide first, then Horner at width 16 ---
    zgemm_kernel<<<gD, db, 0, stream>>>(h, W2, b2, dinv, z0, ZS, N_NODES);

    gather16_kernel<0><<<gW, TB, 0, stream>>>(rowptr, eidx, dinv, z3p, z2, tAp);
    gather16_kernel<0><<<gW, TB, 0, stream>>>(rowptr, eidx, dinv, tAp, z1, tBp);
    gather16_kernel<1><<<gW, TB, 0, stream>>>(rowptr, eidx, dinv, tBp, z0, out);
}

// Round 5
// 439.830 us; speedup vs baseline: 4.2591x; 1.1085x over previous
//
#include <hip/hip_runtime.h>

typedef unsigned int uint;

#define N_NODES 100000
#define N_EDGES 1600000
#define FEAT 32
#define HID 64
#define NCLS 10

#define BUCKET_SHIFT 8
#define NBUCKET 391              // ceil(100000 / 256)
#define NCB 256                  // blocks for bucket hist/scatter passes
#define CHUNK ((N_EDGES + NCB - 1) / NCB)   // 6250
#define BH_N (NBUCKET * NCB)     // 100096
#define NB_BH ((BH_N + 255) / 256)          // 391
#define CAP 6144                 // LDS staging capacity per bucket

// ---------------- bf16 pack/unpack helpers ----------------

__device__ __forceinline__ uint pack_bf16(float lo, float hi) {
    uint a = __float_as_uint(lo);
    uint b = __float_as_uint(hi);
    a = a + 0x7fffu + ((a >> 16) & 1u);
    b = b + 0x7fffu + ((b >> 16) & 1u);
    return (a >> 16) | (b & 0xffff0000u);
}
__device__ __forceinline__ float unp_lo(uint v) { return __uint_as_float(v << 16); }
__device__ __forceinline__ float unp_hi(uint v) { return __uint_as_float(v & 0xffff0000u); }

// ---------------- two-level counting sort: CSR build ----------------

__global__ void bucket_hist(const int* __restrict__ col, int* __restrict__ blockhist) {
    __shared__ int lh[NBUCKET];
    int blk = blockIdx.x;
    for (int i = threadIdx.x; i < NBUCKET; i += 256) lh[i] = 0;
    __syncthreads();
    int e0 = blk * CHUNK;
    int e1 = min(e0 + CHUNK, N_EDGES);
    for (int e = e0 + threadIdx.x; e < e1; e += 256)
        atomicAdd(&lh[col[e] >> BUCKET_SHIFT], 1);
    __syncthreads();
    for (int i = threadIdx.x; i < NBUCKET; i += 256)
        blockhist[i * NCB + blk] = lh[i];
}

__global__ void scanA_kernel(const int* __restrict__ src, int* __restrict__ dst,
                             int* __restrict__ bsum, int n) {
    __shared__ int s[256];
    int gid = blockIdx.x * 256 + threadIdx.x;
    int v = (gid < n) ? src[gid] : 0;
    s[threadIdx.x] = v;
    __syncthreads();
    for (int off = 1; off < 256; off <<= 1) {
        int t = (threadIdx.x >= off) ? s[threadIdx.x - off] : 0;
        __syncthreads();
        s[threadIdx.x] += t;
        __syncthreads();
    }
    if (gid < n) dst[gid] = s[threadIdx.x] - v;  // exclusive within block
    if (threadIdx.x == 255) bsum[blockIdx.x] = s[255];
}

__global__ void scanB_kernel(int* __restrict__ bsum, int nb) {
    __shared__ int s[512];
    int v = (threadIdx.x < nb) ? bsum[threadIdx.x] : 0;
    s[threadIdx.x] = v;
    __syncthreads();
    for (int off = 1; off < 512; off <<= 1) {
        int t = (threadIdx.x >= off) ? s[threadIdx.x - off] : 0;
        __syncthreads();
        s[threadIdx.x] += t;
        __syncthreads();
    }
    if (threadIdx.x < nb) bsum[threadIdx.x] = s[threadIdx.x] - v;  // exclusive
}

__global__ void scanC_add(int* __restrict__ dst, const int* __restrict__ bsum, int n) {
    int gid = blockIdx.x * 256 + threadIdx.x;
    if (gid < n) dst[gid] += bsum[blockIdx.x];
}

__global__ void bucket_scatter(const int* __restrict__ row, const int* __restrict__ col,
                               const int* __restrict__ base, int* __restrict__ packed) {
    __shared__ int lcnt[NBUCKET];
    __shared__ int lbase[NBUCKET];
    int blk = blockIdx.x;
    for (int i = threadIdx.x; i < NBUCKET; i += 256) {
        lcnt[i] = 0;
        lbase[i] = base[i * NCB + blk];
    }
    __syncthreads();
    int e0 = blk * CHUNK;
    int e1 = min(e0 + CHUNK, N_EDGES);
    for (int e = e0 + threadIdx.x; e < e1; e += 256) {
        int c = col[e];
        int r = row[e];
        int b = c >> BUCKET_SHIFT;
        int pos = lbase[b] + atomicAdd(&lcnt[b], 1);
        packed[pos] = (r << BUCKET_SHIFT) | (c & 255);
    }
}

__global__ void bucket_sort(const int* __restrict__ base, const int* __restrict__ packed,
                            int* __restrict__ rowptr, int* __restrict__ eidx,
                            float* __restrict__ dinv) {
    __shared__ int stage[CAP];
    __shared__ int cnt[256];
    __shared__ int lscan[256];
    int b = blockIdx.x;
    int tid = threadIdx.x;
    int s = base[b * NCB];
    int e = (b == NBUCKET - 1) ? N_EDGES : base[(b + 1) * NCB];
    int m = e - s;
    bool fits = (m <= CAP);
    cnt[tid] = 0;
    __syncthreads();
    for (int i = tid; i < m; i += 256) {
        int p = packed[s + i];
        if (fits) stage[i] = p;
        atomicAdd(&cnt[p & 255], 1);
    }
    __syncthreads();
    int node = (b << BUCKET_SHIFT) + tid;
    int c = cnt[tid];
    if (node < N_NODES) dinv[node] = (c > 0) ? rsqrtf((float)c) : 0.0f;
    lscan[tid] = c;
    __syncthreads();
    for (int off = 1; off < 256; off <<= 1) {
        int t = (tid >= off) ? lscan[tid - off] : 0;
        __syncthreads();
        lscan[tid] += t;
        __syncthreads();
    }
    int excl = lscan[tid] - c;
    if (node < N_NODES) rowptr[node] = s + excl;
    if (b == NBUCKET - 1 && tid == 0) rowptr[N_NODES] = N_EDGES;
    __syncthreads();
    lscan[tid] = excl;
    cnt[tid] = 0;
    __syncthreads();
    for (int i = tid; i < m; i += 256) {
        int p = fits ? stage[i] : packed[s + i];
        int cl = p & 255;
        int pos = lscan[cl] + atomicAdd(&cnt[cl], 1);
        eidx[s + pos] = p >> BUCKET_SHIFT;
    }
}

// ---------------- prescale: t0 = bf16(dinv * x), packed pairs ----------------

__global__ void prescale_kernel(const float* __restrict__ x, const float* __restrict__ dinv,
                                uint* __restrict__ t0) {
    int i = blockIdx.x * 256 + threadIdx.x;
    if (i < N_NODES * 16) {
        int node = i >> 4, fp = i & 15;
        float dv = dinv[node];
        t0[i] = pack_bf16(x[node * 32 + 2 * fp] * dv, x[node * 32 + 2 * fp + 1] * dv);
    }
}

// ---------------- gather hops ----------------

// 32-wide bf16: pout[c] = bf16(dinv[c]*sum), preout = bf16(dinv^2*sum)
template <int WP>
__global__ void gather32_kernel(const int* __restrict__ rowptr, const int* __restrict__ eidx,
                                const float* __restrict__ dinv, const uint* __restrict__ src,
                                uint* __restrict__ pout, uint* __restrict__ preout) {
    int node = (blockIdx.x * blockDim.x + threadIdx.x) >> 6;
    if (node >= N_NODES) return;
    int lane = threadIdx.x & 63;
    int fp = lane & 15;   // feature pair
    int g = lane >> 4;    // 4 edge groups
    int s = rowptr[node], e = rowptr[node + 1];
    float acc0 = 0.0f, acc1 = 0.0f;
    int base = (s & ~3) + g * 4;
    for (int b = base; b < e; b += 16) {
        int4 q = *(const int4*)(eidx + b);
        uint v0 = (b     >= s && b     < e) ? src[q.x * 16 + fp] : 0u;
        uint v1 = (b + 1 >= s && b + 1 < e) ? src[q.y * 16 + fp] : 0u;
        uint v2 = (b + 2 >= s && b + 2 < e) ? src[q.z * 16 + fp] : 0u;
        uint v3 = (b + 3 >= s && b + 3 < e) ? src[q.w * 16 + fp] : 0u;
        acc0 += unp_lo(v0) + unp_lo(v1) + unp_lo(v2) + unp_lo(v3);
        acc1 += unp_hi(v0) + unp_hi(v1) + unp_hi(v2) + unp_hi(v3);
    }
    acc0 += __shfl_xor(acc0, 16);
    acc0 += __shfl_xor(acc0, 32);
    acc1 += __shfl_xor(acc1, 16);
    acc1 += __shfl_xor(acc1, 32);
    if (lane < 16) {
        float dv = dinv[node];
        pout[node * 16 + fp] = pack_bf16(dv * acc0, dv * acc1);
        if (WP) {
            float d2 = dv * dv;
            preout[node * 16 + fp] = pack_bf16(d2 * acc0, d2 * acc1);
        }
    }
}

// 16-wide f32 Horner step (unchanged from round 4)
template <int FINAL>
__global__ void gather16_kernel(const int* __restrict__ rowptr, const int* __restrict__ eidx,
                                const float* __restrict__ dinv, const float* __restrict__ src,
                                const float* __restrict__ add, float* __restrict__ outv) {
    int node = (blockIdx.x * blockDim.x + threadIdx.x) >> 6;
    if (node >= N_NODES) return;
    int lane = threadIdx.x & 63;
    int f = lane & 15;
    int g = lane >> 4;
    int s = rowptr[node], e = rowptr[node + 1];
    float acc = 0.0f;
    int base = (s & ~3) + g * 4;
    for (int b = base; b < e; b += 16) {
        int4 q = *(const int4*)(eidx + b);
        float v0 = (b     >= s && b     < e) ? src[q.x * 16 + f] : 0.0f;
        float v1 = (b + 1 >= s && b + 1 < e) ? src[q.y * 16 + f] : 0.0f;
        float v2 = (b + 2 >= s && b + 2 < e) ? src[q.z * 16 + f] : 0.0f;
        float v3 = (b + 3 >= s && b + 3 < e) ? src[q.w * 16 + f] : 0.0f;
        acc += v0 + v1 + v2 + v3;
    }
    acc += __shfl_xor(acc, 16);
    acc += __shfl_xor(acc, 32);
    float dv = dinv[node];
    float v = add[node * 16 + f] + dv * acc;
    if (!FINAL) {
        if (lane < 16) outv[node * 16 + f] = dv * v;
    } else {
        float l = (f < NCLS) ? v : -1e30f;
        float m = l;
        m = fmaxf(m, __shfl_xor(m, 1));
        m = fmaxf(m, __shfl_xor(m, 2));
        m = fmaxf(m, __shfl_xor(m, 4));
        m = fmaxf(m, __shfl_xor(m, 8));
        float ex = (f < NCLS) ? __expf(l - m) : 0.0f;
        ex += __shfl_xor(ex, 1);
        ex += __shfl_xor(ex, 2);
        ex += __shfl_xor(ex, 4);
        ex += __shfl_xor(ex, 8);
        float ls = logf(ex) + m;
        if (lane < 16 && f < NCLS) outv[node * NCLS + f] = l - ls;
    }
}

// ---------------- dense layer 1: h = relu([x|p1|p2|p3] @ W1stack + b1) ----------------
// 32 rows/block, 8 rows/wave, k-unroll x4 with float4 broadcast H reads.

__global__ void dense1_kernel(const float* __restrict__ x, const uint* __restrict__ p1,
                              const uint* __restrict__ p2, const uint* __restrict__ p3,
                              const float* __restrict__ W1, const float* __restrict__ b1,
                              float* __restrict__ h) {
    __shared__ float Ws[128 * 64];   // 32 KB, [k][c]
    __shared__ float Hs[32][128];    // 16 KB
    int tid = threadIdx.x;
    int tx = tid & 63;
    int wv = tid >> 6;

    for (int i = tid; i < 128 * 64; i += 256) Ws[i] = W1[i];

    int row0 = blockIdx.x * 32;
    for (int i = tid; i < 32 * 64; i += 256) {
        int rr = i >> 6, pp = i & 63;
        int r = row0 + rr;
        int blk = pp >> 4, fp = pp & 15;
        float lo, hi;
        if (blk == 0) {
            lo = x[r * 32 + 2 * fp];
            hi = x[r * 32 + 2 * fp + 1];
        } else {
            const uint* p = (blk == 1) ? p1 : (blk == 2) ? p2 : p3;
            uint v = p[r * 16 + fp];
            lo = unp_lo(v);
            hi = unp_hi(v);
        }
        Hs[rr][blk * 32 + 2 * fp] = lo;
        Hs[rr][blk * 32 + 2 * fp + 1] = hi;
    }
    __syncthreads();

    float a[8] = {0, 0, 0, 0, 0, 0, 0, 0};
    int rb = wv * 8;
#pragma unroll 4
    for (int k = 0; k < 128; k += 4) {
        float w0 = Ws[(k + 0) * 64 + tx];
        float w1 = Ws[(k + 1) * 64 + tx];
        float w2 = Ws[(k + 2) * 64 + tx];
        float w3 = Ws[(k + 3) * 64 + tx];
#pragma unroll
        for (int rr = 0; rr < 8; rr++) {
            float4 hv = *(const float4*)&Hs[rb + rr][k];
            a[rr] += hv.x * w0 + hv.y * w1 + hv.z * w2 + hv.w * w3;
        }
    }
    float bb = b1[tx];
#pragma unroll
    for (int rr = 0; rr < 8; rr++) {
        int r = row0 + rb + rr;
        h[r * HID + tx] = fmaxf(a[rr] + bb, 0.0f);
    }
}

// ---------------- layer-2 projection: z_k = h @ W2[k] (+b2 on k=0; k=3 pre-scaled) ----------------

__global__ void zgemm_kernel(const float* __restrict__ h, const float* __restrict__ W2,
                             const float* __restrict__ b2, const float* __restrict__ dinv,
                             float* __restrict__ zbase, int zstride) {
    __shared__ float Ws[64 * 64];   // [kk][khop*16+j], 16 KB
    __shared__ float Hs[32][64];    // 8 KB
    int tid = threadIdx.x;
    int tx = tid & 63;
    int wv = tid >> 6;

    for (int i = tid; i < 64 * 64; i += 256) {
        int kk = i >> 6, c = i & 63;
        int khop = c >> 4, j = c & 15;
        Ws[i] = (j < NCLS) ? W2[(khop * HID + kk) * NCLS + j] : 0.0f;
    }

    int row0 = blockIdx.x * 32;
    for (int i = tid; i < 32 * 64; i += 256) {
        int rr = i >> 6, kk = i & 63;
        Hs[rr][kk] = h[(row0 + rr) * HID + kk];
    }
    __syncthreads();

    float a[8] = {0, 0, 0, 0, 0, 0, 0, 0};
    int rb = wv * 8;
#pragma unroll 4
    for (int kk = 0; kk < 64; kk += 4) {
        float w0 = Ws[(kk + 0) * 64 + tx];
        float w1 = Ws[(kk + 1) * 64 + tx];
        float w2 = Ws[(kk + 2) * 64 + tx];
        float w3 = Ws[(kk + 3) * 64 + tx];
#pragma unroll
        for (int rr = 0; rr < 8; rr++) {
            float4 hv = *(const float4*)&Hs[rb + rr][kk];
            a[rr] += hv.x * w0 + hv.y * w1 + hv.z * w2 + hv.w * w3;
        }
    }
    int khop = tx >> 4, j = tx & 15;
    float bb = (khop == 0 && j < NCLS) ? b2[j] : 0.0f;
    float* zk = zbase + (size_t)khop * zstride;
#pragma unroll
    for (int rr = 0; rr < 8; rr++) {
        int r = row0 + rb + rr;
        float v = a[rr] + bb;
        if (khop == 3) v *= dinv[r];
        zk[r * 16 + j] = v;
    }
}

// ---------------- launcher ----------------

extern "C" void kernel_launch(void* const* d_in, const int* in_sizes, int n_in,
                              void* d_out, int out_size, void* d_ws, size_t ws_size,
                              hipStream_t stream) {
    const float* x  = (const float*)d_in[0];
    const int*   ei = (const int*)d_in[1];
    const float* W1 = (const float*)d_in[2];
    const float* b1 = (const float*)d_in[3];
    const float* W2 = (const float*)d_in[4];
    const float* b2 = (const float*)d_in[5];
    float* out = (float*)d_out;

    const int* row = ei;
    const int* col = ei + N_EDGES;

    float* w = (float*)d_ws;
    size_t o = 0;
    auto alloc = [&](size_t nel) { float* p = w + o; o += (nel + 63) & ~(size_t)63; return p; };

    int*   rowptr = (int*)alloc(N_NODES + 1);
    int*   bsum   = (int*)alloc(512);
    float* dinv   = alloc(N_NODES);
    int*   eidx   = (int*)alloc(N_EDGES + 16);
    float* bufA   = alloc((size_t)N_NODES * 32);
    float* bufB   = alloc((size_t)N_NODES * 32);
    float* bufC   = alloc((size_t)N_NODES * 32);
    float* bufD   = alloc((size_t)N_NODES * 32);
    float* h      = alloc((size_t)N_NODES * HID);

    // CSR-build temporaries alias later buffers (build completes first)
    int* blockhist = (int*)bufB;
    int* bhbase    = (int*)bufC;
    int* packed    = (int*)h;

    // layer-1 bf16 buffers (each 100k x 16 uints = 6.4 MB)
    uint* t0  = (uint*)bufA;
    uint* p1  = (uint*)bufB;
    uint* p1p = (uint*)bufC;
    uint* p2  = (uint*)bufD;
    uint* p2p = (uint*)bufA;   // t0 dead after hop1
    uint* p3  = (uint*)bufC;   // p1p dead after hop2
    // layer-2 f32 z buffers (each 100k x 16 f32 = 6.4 MB)
    const int ZS = N_NODES * 16;
    float* z0  = bufA;
    float* z2  = bufB;
    float* z3p = bufB + ZS;
    float* tAp = bufC;
    float* tBp = bufC + ZS;
    float* z1  = bufA + ZS;

    const int TB = 256;
    const int gW = (N_NODES * 64) / TB;  // 25000: one wave per node

    // --- CSR build ---
    bucket_hist<<<NCB, TB, 0, stream>>>(col, blockhist);
    scanA_kernel<<<NB_BH, TB, 0, stream>>>(blockhist, bhbase, bsum, BH_N);
    scanB_kernel<<<1, 512, 0, stream>>>(bsum, NB_BH);
    scanC_add<<<NB_BH, TB, 0, stream>>>(bhbase, bsum, BH_N);
    bucket_scatter<<<NCB, TB, 0, stream>>>(row, col, bhbase, packed);
    bucket_sort<<<NBUCKET, TB, 0, stream>>>(bhbase, packed, rowptr, eidx, dinv);

    // --- layer 1 (bf16 propagation) ---
    prescale_kernel<<<(N_NODES * 16 + TB - 1) / TB, TB, 0, stream>>>(x, dinv, t0);
    gather32_kernel<1><<<gW, TB, 0, stream>>>(rowptr, eidx, dinv, t0,  p1, p1p);
    gather32_kernel<1><<<gW, TB, 0, stream>>>(rowptr, eidx, dinv, p1p, p2, p2p);
    gather32_kernel<0><<<gW, TB, 0, stream>>>(rowptr, eidx, dinv, p2p, p3, nullptr);

    int gD = N_NODES / 32;  // 3125, exact
    dense1_kernel<<<gD, TB, 0, stream>>>(x, p1, p2, p3, W1, b1, h);

    // --- layer 2: project to 10-wide first, then Horner at width 16 (f32) ---
    zgemm_kernel<<<gD, TB, 0, stream>>>(h, W2, b2, dinv, z0, ZS);

    gather16_kernel<0><<<gW, TB, 0, stream>>>(rowptr, eidx, dinv, z3p, z2, tAp);
    gather16_kernel<0><<<gW, TB, 0, stream>>>(rowptr, eidx, dinv, tAp, z1, tBp);
    gather16_kernel<1><<<gW, TB, 0, stream>>>(rowptr, eidx, dinv, tBp, z0, out);
}

// Round 6
// 346.403 us; speedup vs baseline: 5.4078x; 1.2697x over previous
//
#include <hip/hip_runtime.h>

typedef unsigned int uint;
typedef short s8v __attribute__((ext_vector_type(8)));
typedef float f4v __attribute__((ext_vector_type(4)));

#define N_NODES 100000
#define N_EDGES 1600000
#define FEAT 32
#define HID 64
#define NCLS 10

#define BUCKET_SHIFT 8
#define NBUCKET 391              // ceil(100000 / 256)
#define NCB 256                  // blocks for bucket hist/scatter passes
#define CHUNK ((N_EDGES + NCB - 1) / NCB)   // 6250
#define BH_N (NBUCKET * NCB)     // 100096
#define NB_BH ((BH_N + 255) / 256)          // 391
#define CAP 6144                 // LDS staging capacity per bucket
#define LROW 65                  // padded LDS row stride (f32 words)

// ---------------- bf16 pack/unpack helpers ----------------

__device__ __forceinline__ uint pack_bf16(float lo, float hi) {
    uint a = __float_as_uint(lo);
    uint b = __float_as_uint(hi);
    a = a + 0x7fffu + ((a >> 16) & 1u);
    b = b + 0x7fffu + ((b >> 16) & 1u);
    return (a >> 16) | (b & 0xffff0000u);
}
__device__ __forceinline__ float unp_lo(uint v) { return __uint_as_float(v << 16); }
__device__ __forceinline__ float unp_hi(uint v) { return __uint_as_float(v & 0xffff0000u); }

__device__ __forceinline__ s8v to_s8(uint4 u) {
    union { uint4 u; s8v s; } x;
    x.u = u;
    return x.s;
}

// ---------------- two-level counting sort: CSR build ----------------

__global__ void bucket_hist(const int* __restrict__ col, int* __restrict__ blockhist) {
    __shared__ int lh[NBUCKET];
    int blk = blockIdx.x;
    for (int i = threadIdx.x; i < NBUCKET; i += 256) lh[i] = 0;
    __syncthreads();
    int e0 = blk * CHUNK;
    int e1 = min(e0 + CHUNK, N_EDGES);
    for (int e = e0 + threadIdx.x; e < e1; e += 256)
        atomicAdd(&lh[col[e] >> BUCKET_SHIFT], 1);
    __syncthreads();
    for (int i = threadIdx.x; i < NBUCKET; i += 256)
        blockhist[i * NCB + blk] = lh[i];
}

__global__ void scanA_kernel(const int* __restrict__ src, int* __restrict__ dst,
                             int* __restrict__ bsum, int n) {
    __shared__ int s[256];
    int gid = blockIdx.x * 256 + threadIdx.x;
    int v = (gid < n) ? src[gid] : 0;
    s[threadIdx.x] = v;
    __syncthreads();
    for (int off = 1; off < 256; off <<= 1) {
        int t = (threadIdx.x >= off) ? s[threadIdx.x - off] : 0;
        __syncthreads();
        s[threadIdx.x] += t;
        __syncthreads();
    }
    if (gid < n) dst[gid] = s[threadIdx.x] - v;
    if (threadIdx.x == 255) bsum[blockIdx.x] = s[255];
}

__global__ void scanB_kernel(int* __restrict__ bsum, int nb) {
    __shared__ int s[512];
    int v = (threadIdx.x < nb) ? bsum[threadIdx.x] : 0;
    s[threadIdx.x] = v;
    __syncthreads();
    for (int off = 1; off < 512; off <<= 1) {
        int t = (threadIdx.x >= off) ? s[threadIdx.x - off] : 0;
        __syncthreads();
        s[threadIdx.x] += t;
        __syncthreads();
    }
    if (threadIdx.x < nb) bsum[threadIdx.x] = s[threadIdx.x] - v;
}

__global__ void scanC_add(int* __restrict__ dst, const int* __restrict__ bsum, int n) {
    int gid = blockIdx.x * 256 + threadIdx.x;
    if (gid < n) dst[gid] += bsum[blockIdx.x];
}

__global__ void bucket_scatter(const int* __restrict__ row, const int* __restrict__ col,
                               const int* __restrict__ base, int* __restrict__ packed) {
    __shared__ int lcnt[NBUCKET];
    __shared__ int lbase[NBUCKET];
    int blk = blockIdx.x;
    for (int i = threadIdx.x; i < NBUCKET; i += 256) {
        lcnt[i] = 0;
        lbase[i] = base[i * NCB + blk];
    }
    __syncthreads();
    int e0 = blk * CHUNK;
    int e1 = min(e0 + CHUNK, N_EDGES);
    for (int e = e0 + threadIdx.x; e < e1; e += 256) {
        int c = col[e];
        int r = row[e];
        int b = c >> BUCKET_SHIFT;
        int pos = lbase[b] + atomicAdd(&lcnt[b], 1);
        packed[pos] = (r << BUCKET_SHIFT) | (c & 255);
    }
}

__global__ void bucket_sort(const int* __restrict__ base, const int* __restrict__ packed,
                            int* __restrict__ rowptr, int* __restrict__ eidx,
                            float* __restrict__ dinv) {
    __shared__ int stage[CAP];
    __shared__ int cnt[256];
    __shared__ int lscan[256];
    int b = blockIdx.x;
    int tid = threadIdx.x;
    int s = base[b * NCB];
    int e = (b == NBUCKET - 1) ? N_EDGES : base[(b + 1) * NCB];
    int m = e - s;
    bool fits = (m <= CAP);
    cnt[tid] = 0;
    __syncthreads();
    for (int i = tid; i < m; i += 256) {
        int p = packed[s + i];
        if (fits) stage[i] = p;
        atomicAdd(&cnt[p & 255], 1);
    }
    __syncthreads();
    int node = (b << BUCKET_SHIFT) + tid;
    int c = cnt[tid];
    if (node < N_NODES) dinv[node] = (c > 0) ? rsqrtf((float)c) : 0.0f;
    lscan[tid] = c;
    __syncthreads();
    for (int off = 1; off < 256; off <<= 1) {
        int t = (tid >= off) ? lscan[tid - off] : 0;
        __syncthreads();
        lscan[tid] += t;
        __syncthreads();
    }
    int excl = lscan[tid] - c;
    if (node < N_NODES) rowptr[node] = s + excl;
    if (b == NBUCKET - 1 && tid == 0) rowptr[N_NODES] = N_EDGES;
    __syncthreads();
    lscan[tid] = excl;
    cnt[tid] = 0;
    __syncthreads();
    for (int i = tid; i < m; i += 256) {
        int p = fits ? stage[i] : packed[s + i];
        int cl = p & 255;
        int pos = lscan[cl] + atomicAdd(&cnt[cl], 1);
        eidx[s + pos] = p >> BUCKET_SHIFT;
    }
}

// ---------------- prescale: t0 = bf16(dinv * x), packed pairs ----------------

__global__ void prescale_kernel(const float* __restrict__ x, const float* __restrict__ dinv,
                                uint* __restrict__ t0) {
    int i = blockIdx.x * 256 + threadIdx.x;
    if (i < N_NODES * 16) {
        int node = i >> 4, fp = i & 15;
        float dv = dinv[node];
        t0[i] = pack_bf16(x[node * 32 + 2 * fp] * dv, x[node * 32 + 2 * fp + 1] * dv);
    }
}

// ---------------- gather hops ----------------

template <int WP>
__global__ void gather32_kernel(const int* __restrict__ rowptr, const int* __restrict__ eidx,
                                const float* __restrict__ dinv, const uint* __restrict__ src,
                                uint* __restrict__ pout, uint* __restrict__ preout) {
    int node = (blockIdx.x * blockDim.x + threadIdx.x) >> 6;
    if (node >= N_NODES) return;
    int lane = threadIdx.x & 63;
    int fp = lane & 15;
    int g = lane >> 4;
    int s = rowptr[node], e = rowptr[node + 1];
    float acc0 = 0.0f, acc1 = 0.0f;
    int base = (s & ~3) + g * 4;
    for (int b = base; b < e; b += 16) {
        int4 q = *(const int4*)(eidx + b);
        uint v0 = (b     >= s && b     < e) ? src[q.x * 16 + fp] : 0u;
        uint v1 = (b + 1 >= s && b + 1 < e) ? src[q.y * 16 + fp] : 0u;
        uint v2 = (b + 2 >= s && b + 2 < e) ? src[q.z * 16 + fp] : 0u;
        uint v3 = (b + 3 >= s && b + 3 < e) ? src[q.w * 16 + fp] : 0u;
        acc0 += unp_lo(v0) + unp_lo(v1) + unp_lo(v2) + unp_lo(v3);
        acc1 += unp_hi(v0) + unp_hi(v1) + unp_hi(v2) + unp_hi(v3);
    }
    acc0 += __shfl_xor(acc0, 16);
    acc0 += __shfl_xor(acc0, 32);
    acc1 += __shfl_xor(acc1, 16);
    acc1 += __shfl_xor(acc1, 32);
    if (lane < 16) {
        float dv = dinv[node];
        pout[node * 16 + fp] = pack_bf16(dv * acc0, dv * acc1);
        if (WP) {
            float d2 = dv * dv;
            preout[node * 16 + fp] = pack_bf16(d2 * acc0, d2 * acc1);
        }
    }
}

template <int FINAL>
__global__ void gather16_kernel(const int* __restrict__ rowptr, const int* __restrict__ eidx,
                                const float* __restrict__ dinv, const float* __restrict__ src,
                                const float* __restrict__ add, float* __restrict__ outv) {
    int node = (blockIdx.x * blockDim.x + threadIdx.x) >> 6;
    if (node >= N_NODES) return;
    int lane = threadIdx.x & 63;
    int f = lane & 15;
    int g = lane >> 4;
    int s = rowptr[node], e = rowptr[node + 1];
    float acc = 0.0f;
    int base = (s & ~3) + g * 4;
    for (int b = base; b < e; b += 16) {
        int4 q = *(const int4*)(eidx + b);
        float v0 = (b     >= s && b     < e) ? src[q.x * 16 + f] : 0.0f;
        float v1 = (b + 1 >= s && b + 1 < e) ? src[q.y * 16 + f] : 0.0f;
        float v2 = (b + 2 >= s && b + 2 < e) ? src[q.z * 16 + f] : 0.0f;
        float v3 = (b + 3 >= s && b + 3 < e) ? src[q.w * 16 + f] : 0.0f;
        acc += v0 + v1 + v2 + v3;
    }
    acc += __shfl_xor(acc, 16);
    acc += __shfl_xor(acc, 32);
    float dv = dinv[node];
    float v = add[node * 16 + f] + dv * acc;
    if (!FINAL) {
        if (lane < 16) outv[node * 16 + f] = dv * v;
    } else {
        float l = (f < NCLS) ? v : -1e30f;
        float m = l;
        m = fmaxf(m, __shfl_xor(m, 1));
        m = fmaxf(m, __shfl_xor(m, 2));
        m = fmaxf(m, __shfl_xor(m, 4));
        m = fmaxf(m, __shfl_xor(m, 8));
        float ex = (f < NCLS) ? __expf(l - m) : 0.0f;
        ex += __shfl_xor(ex, 1);
        ex += __shfl_xor(ex, 2);
        ex += __shfl_xor(ex, 4);
        ex += __shfl_xor(ex, 8);
        float ls = logf(ex) + m;
        if (lane < 16 && f < NCLS) outv[node * NCLS + f] = l - ls;
    }
}

// ---------------- weight pre-pack into B-fragment order (bf16) ----------------
// Wf1[((nt*4+ks)*64 + lane)*4 + vj] = pack(W1[k0][n], W1[k0+1][n]),
//   k0 = ks*32 + (lane>>4)*8 + 2*vj, n = nt*16 + (lane&15)
// Wf2[((nt*2+ks)*64 + lane)*4 + vj] likewise from W2[nt][kk][j<10], zero-padded.

__global__ void wfprep_kernel(const float* __restrict__ W1, const float* __restrict__ W2,
                              uint* __restrict__ wf1, uint* __restrict__ wf2) {
    int idx = blockIdx.x * 256 + threadIdx.x;
    if (idx < 4096) {
        int vj = idx & 3, frag = idx >> 2;
        int lane = frag & 63, ks = (frag >> 6) & 3, nt = frag >> 8;
        int g = lane >> 4, c = lane & 15;
        int k0 = ks * 32 + g * 8 + 2 * vj;
        int n = nt * 16 + c;
        wf1[idx] = pack_bf16(W1[k0 * 64 + n], W1[(k0 + 1) * 64 + n]);
    } else if (idx < 6144) {
        int i2 = idx - 4096;
        int vj = i2 & 3, frag = i2 >> 2;
        int lane = frag & 63, ks = (frag >> 6) & 1, nt = frag >> 7;
        int g = lane >> 4, c = lane & 15;
        int k0 = ks * 32 + g * 8 + 2 * vj;
        float v0 = (c < NCLS) ? W2[(nt * HID + k0) * NCLS + c] : 0.0f;
        float v1 = (c < NCLS) ? W2[(nt * HID + k0 + 1) * NCLS + c] : 0.0f;
        wf2[i2] = pack_bf16(v0, v1);
    }
}

// ---------------- fused dense: h = relu([x|p1|p2|p3]@W1+b1); z = h@W2stack (+b2, k3*dinv) ----------------
// 4 waves/block, 16 rows/wave, MFMA 16x16x32 bf16, LDS bounce for re-fragmentation.

__global__ __launch_bounds__(256) void dense_fused(
        const float* __restrict__ x, const uint* __restrict__ p1,
        const uint* __restrict__ p2, const uint* __restrict__ p3,
        const uint* __restrict__ wf1, const uint* __restrict__ wf2,
        const float* __restrict__ b1, const float* __restrict__ b2,
        const float* __restrict__ dinv, float* __restrict__ z, int zstride) {
    __shared__ float hls[4 * 16 * LROW];
    int tid = threadIdx.x;
    int wv = tid >> 6, l = tid & 63, g = l >> 4, c = l & 15;
    float* my = hls + wv * 16 * LROW;
    int row0 = blockIdx.x * 64 + wv * 16;
    int ra = row0 + c;
    int rc = min(ra, N_NODES - 1);

    // ---- stage 1: A-frags straight from global ----
    uint4 au0;
    {
        float4 xa = *(const float4*)(x + rc * 32 + g * 8);
        float4 xb = *(const float4*)(x + rc * 32 + g * 8 + 4);
        au0.x = pack_bf16(xa.x, xa.y);
        au0.y = pack_bf16(xa.z, xa.w);
        au0.z = pack_bf16(xb.x, xb.y);
        au0.w = pack_bf16(xb.z, xb.w);
    }
    uint4 au1 = *(const uint4*)(p1 + rc * 16 + g * 4);
    uint4 au2 = *(const uint4*)(p2 + rc * 16 + g * 4);
    uint4 au3 = *(const uint4*)(p3 + rc * 16 + g * 4);
    s8v a0 = to_s8(au0), a1 = to_s8(au1), a2 = to_s8(au2), a3 = to_s8(au3);

    f4v acc[4];
#pragma unroll
    for (int nt = 0; nt < 4; nt++) {
        f4v ac = {0.f, 0.f, 0.f, 0.f};
        const s8v* wp = (const s8v*)(wf1 + (nt * 4) * 64 * 4 + l * 4);
        ac = __builtin_amdgcn_mfma_f32_16x16x32_bf16(a0, wp[0 * 64], ac, 0, 0, 0);
        ac = __builtin_amdgcn_mfma_f32_16x16x32_bf16(a1, wp[1 * 64], ac, 0, 0, 0);
        ac = __builtin_amdgcn_mfma_f32_16x16x32_bf16(a2, wp[2 * 64], ac, 0, 0, 0);
        ac = __builtin_amdgcn_mfma_f32_16x16x32_bf16(a3, wp[3 * 64], ac, 0, 0, 0);
        acc[nt] = ac;
    }

    // ---- epilogue 1: bias + relu -> padded LDS tile ----
#pragma unroll
    for (int nt = 0; nt < 4; nt++) {
        float bb = b1[nt * 16 + c];
#pragma unroll
        for (int reg = 0; reg < 4; reg++) {
            my[(4 * g + reg) * LROW + nt * 16 + c] = fmaxf(acc[nt][reg] + bb, 0.0f);
        }
    }
    __syncthreads();

    // ---- stage 2: re-fragment from LDS, second MFMA ----
    uint4 b2u[2];
#pragma unroll
    for (int ks = 0; ks < 2; ks++) {
        float4 h0 = *(const float4*)&my[c * LROW + ks * 32 + g * 8];
        float4 h1 = *(const float4*)&my[c * LROW + ks * 32 + g * 8 + 4];
        b2u[ks].x = pack_bf16(h0.x, h0.y);
        b2u[ks].y = pack_bf16(h0.z, h0.w);
        b2u[ks].z = pack_bf16(h1.x, h1.y);
        b2u[ks].w = pack_bf16(h1.z, h1.w);
    }
    s8v h0f = to_s8(b2u[0]), h1f = to_s8(b2u[1]);

    f4v acc2[4];
#pragma unroll
    for (int nt = 0; nt < 4; nt++) {
        f4v ac = {0.f, 0.f, 0.f, 0.f};
        const s8v* wp = (const s8v*)(wf2 + (nt * 2) * 64 * 4 + l * 4);
        ac = __builtin_amdgcn_mfma_f32_16x16x32_bf16(h0f, wp[0 * 64], ac, 0, 0, 0);
        ac = __builtin_amdgcn_mfma_f32_16x16x32_bf16(h1f, wp[1 * 64], ac, 0, 0, 0);
        acc2[nt] = ac;
    }

    // ---- epilogue 2: bias (k=0), dinv prescale (k=3), store z ----
#pragma unroll
    for (int nt = 0; nt < 4; nt++) {
        float bb = (nt == 0 && c < NCLS) ? b2[c] : 0.0f;
        float* zk = z + (size_t)nt * zstride;
#pragma unroll
        for (int reg = 0; reg < 4; reg++) {
            int rr = row0 + 4 * g + reg;
            if (rr < N_NODES) {
                float v = acc2[nt][reg] + bb;
                if (nt == 3) v *= dinv[rr];
                zk[rr * 16 + c] = v;
            }
        }
    }
}

// ---------------- launcher ----------------

extern "C" void kernel_launch(void* const* d_in, const int* in_sizes, int n_in,
                              void* d_out, int out_size, void* d_ws, size_t ws_size,
                              hipStream_t stream) {
    const float* x  = (const float*)d_in[0];
    const int*   ei = (const int*)d_in[1];
    const float* W1 = (const float*)d_in[2];
    const float* b1 = (const float*)d_in[3];
    const float* W2 = (const float*)d_in[4];
    const float* b2 = (const float*)d_in[5];
    float* out = (float*)d_out;

    const int* row = ei;
    const int* col = ei + N_EDGES;

    float* w = (float*)d_ws;
    size_t o = 0;
    auto alloc = [&](size_t nel) { float* p = w + o; o += (nel + 63) & ~(size_t)63; return p; };

    int*   rowptr = (int*)alloc(N_NODES + 1);
    int*   bsum   = (int*)alloc(512);
    float* dinv   = alloc(N_NODES);
    uint*  wf1    = (uint*)alloc(4096);
    uint*  wf2    = (uint*)alloc(2048);
    int*   eidx   = (int*)alloc(N_EDGES + 16);
    float* bufA   = alloc((size_t)N_NODES * 32);
    float* bufB   = alloc((size_t)N_NODES * 32);
    float* bufC   = alloc((size_t)N_NODES * 32);
    float* bufD   = alloc((size_t)N_NODES * 32);
    float* h      = alloc((size_t)N_NODES * HID);   // holds z0..z3 after dense

    // CSR-build temporaries alias later buffers (build completes first)
    int* blockhist = (int*)bufB;
    int* bhbase    = (int*)bufC;
    int* packed    = (int*)h;

    // layer-1 bf16 buffers (each 100k x 16 uints = 6.4 MB)
    uint* t0  = (uint*)bufA;
    uint* p1  = (uint*)bufB;
    uint* p1p = (uint*)bufC;
    uint* p2  = (uint*)bufD;
    uint* p2p = (uint*)bufA;   // t0 dead after hop1
    uint* p3  = (uint*)bufC;   // p1p dead after hop2
    // layer-2 f32 z buffers live in h region (p1/p2/p3 stay readable during dense)
    const int ZS = N_NODES * 16;
    float* z0  = h;
    float* z1  = h + ZS;
    float* z2  = h + 2 * (size_t)ZS;
    float* z3p = h + 3 * (size_t)ZS;   // pre-scaled by dinv in dense_fused
    float* tAp = bufC;                 // bufC free after dense_fused
    float* tBp = bufC + ZS;

    const int TB = 256;
    const int gW = (N_NODES * 64) / TB;  // 25000: one wave per node

    // --- CSR build ---
    bucket_hist<<<NCB, TB, 0, stream>>>(col, blockhist);
    scanA_kernel<<<NB_BH, TB, 0, stream>>>(blockhist, bhbase, bsum, BH_N);
    scanB_kernel<<<1, 512, 0, stream>>>(bsum, NB_BH);
    scanC_add<<<NB_BH, TB, 0, stream>>>(bhbase, bsum, BH_N);
    bucket_scatter<<<NCB, TB, 0, stream>>>(row, col, bhbase, packed);
    bucket_sort<<<NBUCKET, TB, 0, stream>>>(bhbase, packed, rowptr, eidx, dinv);

    // --- weight pre-pack (independent of CSR, tiny) ---
    wfprep_kernel<<<24, TB, 0, stream>>>(W1, W2, wf1, wf2);

    // --- layer 1 (bf16 propagation) ---
    prescale_kernel<<<(N_NODES * 16 + TB - 1) / TB, TB, 0, stream>>>(x, dinv, t0);
    gather32_kernel<1><<<gW, TB, 0, stream>>>(rowptr, eidx, dinv, t0,  p1, p1p);
    gather32_kernel<1><<<gW, TB, 0, stream>>>(rowptr, eidx, dinv, p1p, p2, p2p);
    gather32_kernel<0><<<gW, TB, 0, stream>>>(rowptr, eidx, dinv, p2p, p3, nullptr);

    // --- fused dense: both layers' GEMMs on the matrix pipe ---
    int gF = (N_NODES + 63) / 64;  // 1563
    dense_fused<<<gF, TB, 0, stream>>>(x, p1, p2, p3, wf1, wf2, b1, b2, dinv, z0, ZS);

    // --- layer-2 Horner at width 16 (f32) ---
    gather16_kernel<0><<<gW, TB, 0, stream>>>(rowptr, eidx, dinv, z3p, z2, tAp);
    gather16_kernel<0><<<gW, TB, 0, stream>>>(rowptr, eidx, dinv, tAp, z1, tBp);
    gather16_kernel<1><<<gW, TB, 0, stream>>>(rowptr, eidx, dinv, tBp, z0, out);
}

// Round 7
// 284.761 us; speedup vs baseline: 6.5785x; 1.2165x over previous
//
#include <hip/hip_runtime.h>

typedef unsigned int uint;
typedef short s8v __attribute__((ext_vector_type(8)));
typedef float f4v __attribute__((ext_vector_type(4)));

#define N_NODES 100000
#define N_EDGES 1600000
#define FEAT 32
#define HID 64
#define NCLS 10

#define BUCKET_SHIFT 8
#define NBUCKET 391              // ceil(100000 / 256)
#define NCB 256                  // blocks for bucket hist/scatter passes
#define CHUNK ((N_EDGES + NCB - 1) / NCB)   // 6250
#define BH_N (NBUCKET * NCB)     // 100096
#define NB_BH ((BH_N + 255) / 256)          // 391
#define CAP 6144                 // LDS staging capacity per bucket
#define LROW 65                  // padded LDS row stride (f32 words)

// ---------------- bf16 pack/unpack helpers ----------------

__device__ __forceinline__ uint pack_bf16(float lo, float hi) {
    uint a = __float_as_uint(lo);
    uint b = __float_as_uint(hi);
    a = a + 0x7fffu + ((a >> 16) & 1u);
    b = b + 0x7fffu + ((b >> 16) & 1u);
    return (a >> 16) | (b & 0xffff0000u);
}
__device__ __forceinline__ float unp_lo(uint v) { return __uint_as_float(v << 16); }
__device__ __forceinline__ float unp_hi(uint v) { return __uint_as_float(v & 0xffff0000u); }

__device__ __forceinline__ s8v to_s8(uint4 u) {
    union { uint4 u; s8v s; } x;
    x.u = u;
    return x.s;
}

// ---------------- two-level counting sort: CSR build ----------------

__global__ void bucket_hist(const int* __restrict__ col, int* __restrict__ blockhist) {
    __shared__ int lh[NBUCKET];
    int blk = blockIdx.x;
    for (int i = threadIdx.x; i < NBUCKET; i += 256) lh[i] = 0;
    __syncthreads();
    int e0 = blk * CHUNK;
    int e1 = min(e0 + CHUNK, N_EDGES);
    for (int e = e0 + threadIdx.x; e < e1; e += 256)
        atomicAdd(&lh[col[e] >> BUCKET_SHIFT], 1);
    __syncthreads();
    for (int i = threadIdx.x; i < NBUCKET; i += 256)
        blockhist[i * NCB + blk] = lh[i];
}

__global__ void scanA_kernel(const int* __restrict__ src, int* __restrict__ dst,
                             int* __restrict__ bsum, int n) {
    __shared__ int s[256];
    int gid = blockIdx.x * 256 + threadIdx.x;
    int v = (gid < n) ? src[gid] : 0;
    s[threadIdx.x] = v;
    __syncthreads();
    for (int off = 1; off < 256; off <<= 1) {
        int t = (threadIdx.x >= off) ? s[threadIdx.x - off] : 0;
        __syncthreads();
        s[threadIdx.x] += t;
        __syncthreads();
    }
    if (gid < n) dst[gid] = s[threadIdx.x] - v;
    if (threadIdx.x == 255) bsum[blockIdx.x] = s[255];
}

__global__ void scanB_kernel(int* __restrict__ bsum, int nb) {
    __shared__ int s[512];
    int v = (threadIdx.x < nb) ? bsum[threadIdx.x] : 0;
    s[threadIdx.x] = v;
    __syncthreads();
    for (int off = 1; off < 512; off <<= 1) {
        int t = (threadIdx.x >= off) ? s[threadIdx.x - off] : 0;
        __syncthreads();
        s[threadIdx.x] += t;
        __syncthreads();
    }
    if (threadIdx.x < nb) bsum[threadIdx.x] = s[threadIdx.x] - v;
}

__global__ void scanC_add(int* __restrict__ dst, const int* __restrict__ bsum, int n) {
    int gid = blockIdx.x * 256 + threadIdx.x;
    if (gid < n) dst[gid] += bsum[blockIdx.x];
}

__global__ void bucket_scatter(const int* __restrict__ row, const int* __restrict__ col,
                               const int* __restrict__ base, int* __restrict__ packed) {
    __shared__ int lcnt[NBUCKET];
    __shared__ int lbase[NBUCKET];
    int blk = blockIdx.x;
    for (int i = threadIdx.x; i < NBUCKET; i += 256) {
        lcnt[i] = 0;
        lbase[i] = base[i * NCB + blk];
    }
    __syncthreads();
    int e0 = blk * CHUNK;
    int e1 = min(e0 + CHUNK, N_EDGES);
    for (int e = e0 + threadIdx.x; e < e1; e += 256) {
        int c = col[e];
        int r = row[e];
        int b = c >> BUCKET_SHIFT;
        int pos = lbase[b] + atomicAdd(&lcnt[b], 1);
        packed[pos] = (r << BUCKET_SHIFT) | (c & 255);
    }
}

__global__ void bucket_sort(const int* __restrict__ base, const int* __restrict__ packed,
                            int* __restrict__ rowptr, int* __restrict__ eidx,
                            float* __restrict__ dinv) {
    __shared__ int stage[CAP];
    __shared__ int cnt[256];
    __shared__ int lscan[256];
    int b = blockIdx.x;
    int tid = threadIdx.x;
    int s = base[b * NCB];
    int e = (b == NBUCKET - 1) ? N_EDGES : base[(b + 1) * NCB];
    int m = e - s;
    bool fits = (m <= CAP);
    cnt[tid] = 0;
    __syncthreads();
    for (int i = tid; i < m; i += 256) {
        int p = packed[s + i];
        if (fits) stage[i] = p;
        atomicAdd(&cnt[p & 255], 1);
    }
    __syncthreads();
    int node = (b << BUCKET_SHIFT) + tid;
    int c = cnt[tid];
    if (node < N_NODES) dinv[node] = (c > 0) ? rsqrtf((float)c) : 0.0f;
    lscan[tid] = c;
    __syncthreads();
    for (int off = 1; off < 256; off <<= 1) {
        int t = (tid >= off) ? lscan[tid - off] : 0;
        __syncthreads();
        lscan[tid] += t;
        __syncthreads();
    }
    int excl = lscan[tid] - c;
    if (node < N_NODES) rowptr[node] = s + excl;
    if (b == NBUCKET - 1 && tid == 0) rowptr[N_NODES] = N_EDGES;
    __syncthreads();
    lscan[tid] = excl;
    cnt[tid] = 0;
    __syncthreads();
    for (int i = tid; i < m; i += 256) {
        int p = fits ? stage[i] : packed[s + i];
        int cl = p & 255;
        int pos = lscan[cl] + atomicAdd(&cnt[cl], 1);
        eidx[s + pos] = p >> BUCKET_SHIFT;
    }
}

// ---------------- prescale: t0 = bf16(dinv * x), packed pairs ----------------

__global__ void prescale_kernel(const float* __restrict__ x, const float* __restrict__ dinv,
                                uint* __restrict__ t0) {
    int i = blockIdx.x * 256 + threadIdx.x;
    if (i < N_NODES * 16) {
        int node = i >> 4, fp = i & 15;
        float dv = dinv[node];
        t0[i] = pack_bf16(x[node * 32 + 2 * fp] * dv, x[node * 32 + 2 * fp + 1] * dv);
    }
}

// ---------------- gather hops ----------------

// 32-wide bf16 (layer 1), 1 node/wave
template <int WP>
__global__ void gather32_kernel(const int* __restrict__ rowptr, const int* __restrict__ eidx,
                                const float* __restrict__ dinv, const uint* __restrict__ src,
                                uint* __restrict__ pout, uint* __restrict__ preout) {
    int node = (blockIdx.x * blockDim.x + threadIdx.x) >> 6;
    if (node >= N_NODES) return;
    int lane = threadIdx.x & 63;
    int fp = lane & 15;
    int g = lane >> 4;
    int s = rowptr[node], e = rowptr[node + 1];
    float acc0 = 0.0f, acc1 = 0.0f;
    int base = (s & ~3) + g * 4;
    for (int b = base; b < e; b += 16) {
        int4 q = *(const int4*)(eidx + b);
        uint v0 = (b     >= s && b     < e) ? src[q.x * 16 + fp] : 0u;
        uint v1 = (b + 1 >= s && b + 1 < e) ? src[q.y * 16 + fp] : 0u;
        uint v2 = (b + 2 >= s && b + 2 < e) ? src[q.z * 16 + fp] : 0u;
        uint v3 = (b + 3 >= s && b + 3 < e) ? src[q.w * 16 + fp] : 0u;
        acc0 += unp_lo(v0) + unp_lo(v1) + unp_lo(v2) + unp_lo(v3);
        acc1 += unp_hi(v0) + unp_hi(v1) + unp_hi(v2) + unp_hi(v3);
    }
    acc0 += __shfl_xor(acc0, 16);
    acc0 += __shfl_xor(acc0, 32);
    acc1 += __shfl_xor(acc1, 16);
    acc1 += __shfl_xor(acc1, 32);
    if (lane < 16) {
        float dv = dinv[node];
        pout[node * 16 + fp] = pack_bf16(dv * acc0, dv * acc1);
        if (WP) {
            float d2 = dv * dv;
            preout[node * 16 + fp] = pack_bf16(d2 * acc0, d2 * acc1);
        }
    }
}

// 16-wide bf16 Horner step, 2 nodes/wave.
//   v = add + dinv*sum;  FINAL=0: out=bf16(dinv*v)  FINAL=1: out=f32 log_softmax(v)
template <int FINAL>
__global__ void gather16_kernel(const int* __restrict__ rowptr, const int* __restrict__ eidx,
                                const float* __restrict__ dinv, const uint* __restrict__ src,
                                const uint* __restrict__ add, void* __restrict__ outv) {
    int wid = (blockIdx.x * blockDim.x + threadIdx.x) >> 6;
    int lane = threadIdx.x & 63;
    int node = wid * 2 + (lane >> 5);
    if (node >= N_NODES) return;
    int fp = lane & 7;        // feature pair 0..7
    int g = (lane >> 3) & 3;  // 4 edge groups
    int s = rowptr[node], e = rowptr[node + 1];
    float acc0 = 0.0f, acc1 = 0.0f;
    int base = (s & ~3) + g * 4;
    for (int b = base; b < e; b += 16) {
        int4 q = *(const int4*)(eidx + b);
        uint v0 = (b     >= s && b     < e) ? src[q.x * 8 + fp] : 0u;
        uint v1 = (b + 1 >= s && b + 1 < e) ? src[q.y * 8 + fp] : 0u;
        uint v2 = (b + 2 >= s && b + 2 < e) ? src[q.z * 8 + fp] : 0u;
        uint v3 = (b + 3 >= s && b + 3 < e) ? src[q.w * 8 + fp] : 0u;
        acc0 += unp_lo(v0) + unp_lo(v1) + unp_lo(v2) + unp_lo(v3);
        acc1 += unp_hi(v0) + unp_hi(v1) + unp_hi(v2) + unp_hi(v3);
    }
    // reduce over the 4 edge groups (lane bits 3,4)
    acc0 += __shfl_xor(acc0, 8);
    acc0 += __shfl_xor(acc0, 16);
    acc1 += __shfl_xor(acc1, 8);
    acc1 += __shfl_xor(acc1, 16);
    float dv = dinv[node];
    uint av = add[node * 8 + fp];
    float v0 = unp_lo(av) + dv * acc0;
    float v1 = unp_hi(av) + dv * acc1;
    if (!FINAL) {
        if (g == 0) ((uint*)outv)[node * 8 + fp] = pack_bf16(dv * v0, dv * v1);
    } else {
        float l0 = (2 * fp     < NCLS) ? v0 : -1e30f;
        float l1 = (2 * fp + 1 < NCLS) ? v1 : -1e30f;
        float m = fmaxf(l0, l1);
        m = fmaxf(m, __shfl_xor(m, 1));
        m = fmaxf(m, __shfl_xor(m, 2));
        m = fmaxf(m, __shfl_xor(m, 4));
        float ex = ((2 * fp     < NCLS) ? __expf(l0 - m) : 0.0f)
                 + ((2 * fp + 1 < NCLS) ? __expf(l1 - m) : 0.0f);
        ex += __shfl_xor(ex, 1);
        ex += __shfl_xor(ex, 2);
        ex += __shfl_xor(ex, 4);
        float ls = logf(ex) + m;
        if (g == 0 && fp < 5) {
            float2 o = {l0 - ls, l1 - ls};
            *(float2*)((float*)outv + (size_t)node * 10 + 2 * fp) = o;
        }
    }
}

// ---------------- weight pre-pack into B-fragment order (bf16) ----------------

__global__ void wfprep_kernel(const float* __restrict__ W1, const float* __restrict__ W2,
                              uint* __restrict__ wf1, uint* __restrict__ wf2) {
    int idx = blockIdx.x * 256 + threadIdx.x;
    if (idx < 4096) {
        int vj = idx & 3, frag = idx >> 2;
        int lane = frag & 63, ks = (frag >> 6) & 3, nt = frag >> 8;
        int g = lane >> 4, c = lane & 15;
        int k0 = ks * 32 + g * 8 + 2 * vj;
        int n = nt * 16 + c;
        wf1[idx] = pack_bf16(W1[k0 * 64 + n], W1[(k0 + 1) * 64 + n]);
    } else if (idx < 6144) {
        int i2 = idx - 4096;
        int vj = i2 & 3, frag = i2 >> 2;
        int lane = frag & 63, ks = (frag >> 6) & 1, nt = frag >> 7;
        int g = lane >> 4, c = lane & 15;
        int k0 = ks * 32 + g * 8 + 2 * vj;
        float v0 = (c < NCLS) ? W2[(nt * HID + k0) * NCLS + c] : 0.0f;
        float v1 = (c < NCLS) ? W2[(nt * HID + k0 + 1) * NCLS + c] : 0.0f;
        wf2[i2] = pack_bf16(v0, v1);
    }
}

// ---------------- fused dense: h = relu([x|p1|p2|p3]@W1+b1); z = bf16(h@W2stack (+b2, k3*dinv)) ----------------

__global__ __launch_bounds__(256) void dense_fused(
        const float* __restrict__ x, const uint* __restrict__ p1,
        const uint* __restrict__ p2, const uint* __restrict__ p3,
        const uint* __restrict__ wf1, const uint* __restrict__ wf2,
        const float* __restrict__ b1, const float* __restrict__ b2,
        const float* __restrict__ dinv, uint* __restrict__ z, int zstride) {
    __shared__ float hls[4 * 16 * LROW];
    int tid = threadIdx.x;
    int wv = tid >> 6, l = tid & 63, g = l >> 4, c = l & 15;
    float* my = hls + wv * 16 * LROW;
    int row0 = blockIdx.x * 64 + wv * 16;
    int ra = row0 + c;
    int rc = min(ra, N_NODES - 1);

    // ---- stage 1: A-frags straight from global ----
    uint4 au0;
    {
        float4 xa = *(const float4*)(x + rc * 32 + g * 8);
        float4 xb = *(const float4*)(x + rc * 32 + g * 8 + 4);
        au0.x = pack_bf16(xa.x, xa.y);
        au0.y = pack_bf16(xa.z, xa.w);
        au0.z = pack_bf16(xb.x, xb.y);
        au0.w = pack_bf16(xb.z, xb.w);
    }
    uint4 au1 = *(const uint4*)(p1 + rc * 16 + g * 4);
    uint4 au2 = *(const uint4*)(p2 + rc * 16 + g * 4);
    uint4 au3 = *(const uint4*)(p3 + rc * 16 + g * 4);
    s8v a0 = to_s8(au0), a1 = to_s8(au1), a2 = to_s8(au2), a3 = to_s8(au3);

    f4v acc[4];
#pragma unroll
    for (int nt = 0; nt < 4; nt++) {
        f4v ac = {0.f, 0.f, 0.f, 0.f};
        const s8v* wp = (const s8v*)(wf1 + (nt * 4) * 64 * 4 + l * 4);
        ac = __builtin_amdgcn_mfma_f32_16x16x32_bf16(a0, wp[0 * 64], ac, 0, 0, 0);
        ac = __builtin_amdgcn_mfma_f32_16x16x32_bf16(a1, wp[1 * 64], ac, 0, 0, 0);
        ac = __builtin_amdgcn_mfma_f32_16x16x32_bf16(a2, wp[2 * 64], ac, 0, 0, 0);
        ac = __builtin_amdgcn_mfma_f32_16x16x32_bf16(a3, wp[3 * 64], ac, 0, 0, 0);
        acc[nt] = ac;
    }

    // ---- epilogue 1: bias + relu -> padded LDS tile ----
#pragma unroll
    for (int nt = 0; nt < 4; nt++) {
        float bb = b1[nt * 16 + c];
#pragma unroll
        for (int reg = 0; reg < 4; reg++) {
            my[(4 * g + reg) * LROW + nt * 16 + c] = fmaxf(acc[nt][reg] + bb, 0.0f);
        }
    }
    __syncthreads();

    // ---- stage 2: re-fragment from LDS, second MFMA ----
    uint4 b2u[2];
#pragma unroll
    for (int ks = 0; ks < 2; ks++) {
        float4 h0 = *(const float4*)&my[c * LROW + ks * 32 + g * 8];
        float4 h1 = *(const float4*)&my[c * LROW + ks * 32 + g * 8 + 4];
        b2u[ks].x = pack_bf16(h0.x, h0.y);
        b2u[ks].y = pack_bf16(h0.z, h0.w);
        b2u[ks].z = pack_bf16(h1.x, h1.y);
        b2u[ks].w = pack_bf16(h1.z, h1.w);
    }
    s8v h0f = to_s8(b2u[0]), h1f = to_s8(b2u[1]);

    f4v acc2[4];
#pragma unroll
    for (int nt = 0; nt < 4; nt++) {
        f4v ac = {0.f, 0.f, 0.f, 0.f};
        const s8v* wp = (const s8v*)(wf2 + (nt * 2) * 64 * 4 + l * 4);
        ac = __builtin_amdgcn_mfma_f32_16x16x32_bf16(h0f, wp[0 * 64], ac, 0, 0, 0);
        ac = __builtin_amdgcn_mfma_f32_16x16x32_bf16(h1f, wp[1 * 64], ac, 0, 0, 0);
        acc2[nt] = ac;
    }

    // ---- epilogue 2: bias (k=0), dinv prescale (k=3), pack pairs via shfl, store bf16 z ----
#pragma unroll
    for (int nt = 0; nt < 4; nt++) {
        float bb = (nt == 0 && c < NCLS) ? b2[c] : 0.0f;
        uint* zk = z + (size_t)nt * zstride;
#pragma unroll
        for (int reg = 0; reg < 4; reg++) {
            int rr = row0 + 4 * g + reg;
            float v = acc2[nt][reg] + bb;
            if (nt == 3) v *= dinv[min(rr, N_NODES - 1)];
            float vn = __shfl_xor(v, 1);  // col c^1's value
            if (rr < N_NODES && (c & 1) == 0) {
                zk[rr * 8 + (c >> 1)] = pack_bf16(v, vn);
            }
        }
    }
}

// ---------------- launcher ----------------

extern "C" void kernel_launch(void* const* d_in, const int* in_sizes, int n_in,
                              void* d_out, int out_size, void* d_ws, size_t ws_size,
                              hipStream_t stream) {
    const float* x  = (const float*)d_in[0];
    const int*   ei = (const int*)d_in[1];
    const float* W1 = (const float*)d_in[2];
    const float* b1 = (const float*)d_in[3];
    const float* W2 = (const float*)d_in[4];
    const float* b2 = (const float*)d_in[5];
    float* out = (float*)d_out;

    const int* row = ei;
    const int* col = ei + N_EDGES;

    float* w = (float*)d_ws;
    size_t o = 0;
    auto alloc = [&](size_t nel) { float* p = w + o; o += (nel + 63) & ~(size_t)63; return p; };

    int*   rowptr = (int*)alloc(N_NODES + 1);
    int*   bsum   = (int*)alloc(512);
    float* dinv   = alloc(N_NODES);
    uint*  wf1    = (uint*)alloc(4096);
    uint*  wf2    = (uint*)alloc(2048);
    int*   eidx   = (int*)alloc(N_EDGES + 16);
    float* bufA   = alloc((size_t)N_NODES * 32);
    float* bufB   = alloc((size_t)N_NODES * 32);
    float* bufC   = alloc((size_t)N_NODES * 32);
    float* bufD   = alloc((size_t)N_NODES * 32);
    float* h      = alloc((size_t)N_NODES * HID);   // holds z0..z3 after dense

    // CSR-build temporaries alias later buffers (build completes first)
    int* blockhist = (int*)bufB;
    int* bhbase    = (int*)bufC;
    int* packed    = (int*)h;

    // layer-1 bf16 buffers (each 100k x 16 uints = 6.4 MB)
    uint* t0  = (uint*)bufA;
    uint* p1  = (uint*)bufB;
    uint* p1p = (uint*)bufC;
    uint* p2  = (uint*)bufD;
    uint* p2p = (uint*)bufA;   // t0 dead after hop1
    uint* p3  = (uint*)bufC;   // p1p dead after hop2
    // layer-2 bf16 z buffers (each 100k x 8 uints = 3.2 MB) live in h region
    const int ZS = N_NODES * 8;
    uint* z0  = (uint*)h;
    uint* z1  = (uint*)h + ZS;
    uint* z2  = (uint*)h + 2 * (size_t)ZS;
    uint* z3p = (uint*)h + 3 * (size_t)ZS;   // pre-scaled by dinv in dense_fused
    uint* tAp = (uint*)bufC;                 // bufC free after dense_fused
    uint* tBp = (uint*)bufC + ZS;

    const int TB = 256;
    const int gW = (N_NODES * 64) / TB;        // 25000: 1 node/wave kernels
    const int gW2 = ((N_NODES + 1) / 2 * 64 + TB - 1) / TB;  // 12500: 2 nodes/wave

    // --- CSR build ---
    bucket_hist<<<NCB, TB, 0, stream>>>(col, blockhist);
    scanA_kernel<<<NB_BH, TB, 0, stream>>>(blockhist, bhbase, bsum, BH_N);
    scanB_kernel<<<1, 512, 0, stream>>>(bsum, NB_BH);
    scanC_add<<<NB_BH, TB, 0, stream>>>(bhbase, bsum, BH_N);
    bucket_scatter<<<NCB, TB, 0, stream>>>(row, col, bhbase, packed);
    bucket_sort<<<NBUCKET, TB, 0, stream>>>(bhbase, packed, rowptr, eidx, dinv);

    // --- weight pre-pack (tiny) ---
    wfprep_kernel<<<24, TB, 0, stream>>>(W1, W2, wf1, wf2);

    // --- layer 1 (bf16 propagation) ---
    prescale_kernel<<<(N_NODES * 16 + TB - 1) / TB, TB, 0, stream>>>(x, dinv, t0);
    gather32_kernel<1><<<gW, TB, 0, stream>>>(rowptr, eidx, dinv, t0,  p1, p1p);
    gather32_kernel<1><<<gW, TB, 0, stream>>>(rowptr, eidx, dinv, p1p, p2, p2p);
    gather32_kernel<0><<<gW, TB, 0, stream>>>(rowptr, eidx, dinv, p2p, p3, nullptr);

    // --- fused dense: both layers' GEMMs on the matrix pipe ---
    int gF = (N_NODES + 63) / 64;  // 1563
    dense_fused<<<gF, TB, 0, stream>>>(x, p1, p2, p3, wf1, wf2, b1, b2, dinv, z0, ZS);

    // --- layer-2 Horner at width 16 (bf16) ---
    gather16_kernel<0><<<gW2, TB, 0, stream>>>(rowptr, eidx, dinv, z3p, z2, tAp);
    gather16_kernel<0><<<gW2, TB, 0, stream>>>(rowptr, eidx, dinv, tAp, z1, tBp);
    gather16_kernel<1><<<gW2, TB, 0, stream>>>(rowptr, eidx, dinv, tBp, z0, out);
}